// Round 8
// baseline (492.377 us; speedup 1.0000x reference)
//
#include <hip/hip_runtime.h>
#include <math.h>

#define NN   131072   // total inner nodes
#define GG   2048     // graphs
#define NPG  64       // nodes per graph
#define EE   1048576  // inner edges
#define EFN  32768    // outer edges
#define DD   128      // feature dim
#define KK   8        // sortpool k
#define VOCAB 150
#define SRCMASK 0x1FFFF   // NN = 2^17

typedef unsigned short bfu;  // raw 16-bit float bits (fp16 on CSR path)
typedef _Float16 f16x8 __attribute__((ext_vector_type(8)));
typedef float f32x4 __attribute__((ext_vector_type(4)));

static __device__ __forceinline__ bfu f2h(float f) {  // RNE f32 -> fp16 bits
  _Float16 h = (_Float16)f;
  bfu u;
  __builtin_memcpy(&u, &h, 2);
  return u;
}
static __device__ __forceinline__ float h2f(bfu b) {
  _Float16 h;
  __builtin_memcpy(&h, &b, 2);
  return (float)h;
}

// ---------------- utility ----------------
__global__ void fill_f32_kernel(float* __restrict__ p, float v, int nElems) {
  int i = blockIdx.x * 256 + threadIdx.x;
  if (i < nElems) p[i] = v;
}

__global__ void zero_int_kernel(int* __restrict__ p, int nElems) {
  int i = blockIdx.x * 256 + threadIdx.x;
  if (i < nElems) p[i] = 0;
}

__global__ void init_softmax_kernel(float* __restrict__ mx, float* __restrict__ sm, int nElems) {
  int i = blockIdx.x * 256 + threadIdx.x;
  if (i < nElems) { mx[i] = -INFINITY; sm[i] = 0.f; }
}

// x[i] = relu(token_emb[h[node]][d])   (fallback path only)
__global__ void embed_relu_kernel(const float* __restrict__ temb,
                                  const int* __restrict__ h,
                                  float* __restrict__ x, int total) {
  int i = blockIdx.x * 256 + threadIdx.x;
  if (i >= total) return;
  int node = i >> 7, d = i & 127;
  x[i] = fmaxf(temb[h[node] * DD + d], 0.f);
}

// ---------------- small / generic GEMM (fallback) ----------------
template <int KD, int ROWS>
__global__ __launch_bounds__(128) void gemm_kernel(
    const float* __restrict__ A, const float* __restrict__ W,
    const float* __restrict__ bias, float* __restrict__ out,
    int relu_flag) {
  __shared__ float As[ROWS * KD];
  const int row0 = blockIdx.x * ROWS;
  const int tid = threadIdx.x;
  for (int i = tid; i < ROWS * KD; i += 128) As[i] = A[(size_t)row0 * KD + i];
  __syncthreads();
  float acc[ROWS];
#pragma unroll
  for (int r = 0; r < ROWS; r++) acc[r] = 0.f;
  for (int k = 0; k < KD; k++) {
    float w = W[k * 128 + tid];
#pragma unroll
    for (int r = 0; r < ROWS; r++) acc[r] += As[r * KD + k] * w;
  }
  float b = bias ? bias[tid] : 0.f;
#pragma unroll
  for (int r = 0; r < ROWS; r++) {
    float v = acc[r] + b;
    if (relu_flag) v = fmaxf(v, 0.f);
    out[(size_t)(row0 + r) * 128 + tid] = v;
  }
}

// ---------------- vocab layer-1 table: fv = relu(temb) @ W1, logits ----------------
__global__ __launch_bounds__(128) void vocab_l1_kernel(
    const float* __restrict__ temb, const float* __restrict__ W1,
    const float* __restrict__ al1, const float* __restrict__ ar1,
    bfu* __restrict__ fvh, float* __restrict__ elv, float* __restrict__ erv) {
  __shared__ float xs[128];
  __shared__ float rl[128], rr[128];
  int v = blockIdx.x, t = threadIdx.x;
  xs[t] = fmaxf(temb[v * 128 + t], 0.f);
  __syncthreads();
  float acc = 0.f;
  for (int k = 0; k < 128; k++) acc += xs[k] * W1[k * 128 + t];
  fvh[v * 128 + t] = f2h(acc);
  rl[t] = acc * al1[t];
  rr[t] = acc * ar1[t];
  __syncthreads();
  for (int off = 64; off; off >>= 1) {
    if (t < off) { rl[t] += rl[t + off]; rr[t] += rr[t + off]; }
    __syncthreads();
  }
  if (t == 0) { elv[v] = rl[0]; erv[v] = rr[0]; }
}

// ---------------- outer-GAT GEMM + fused logits (fallback path) ----------------
__global__ __launch_bounds__(256) void gemm1024_kernel(
    const float* __restrict__ A, const float* __restrict__ W,
    float* __restrict__ out,
    const float* __restrict__ al, const float* __restrict__ ar,
    float* __restrict__ el, float* __restrict__ er) {
  __shared__ float As[8 * 1024];
  __shared__ float red[8][256];
  const int t = threadIdx.x;
  const int row0 = blockIdx.x * 8;
  for (int idx = t; idx < 8 * 256; idx += 256) {
    int r = idx >> 8, c4 = (idx & 255) << 2;
    *(float4*)&As[r * 1024 + c4] = *(const float4*)(A + (size_t)(row0 + r) * 1024 + c4);
  }
  __syncthreads();
  const int col = t & 127, kh = t >> 7;
  const int k0 = kh * 512;
  float acc[8];
#pragma unroll
  for (int r = 0; r < 8; r++) acc[r] = 0.f;
  for (int k = k0; k < k0 + 512; k += 4) {
    float w0 = W[(size_t)(k + 0) * 128 + col];
    float w1 = W[(size_t)(k + 1) * 128 + col];
    float w2 = W[(size_t)(k + 2) * 128 + col];
    float w3 = W[(size_t)(k + 3) * 128 + col];
#pragma unroll
    for (int r = 0; r < 8; r++) {
      float4 a = *(const float4*)&As[r * 1024 + k];
      acc[r] += a.x * w0 + a.y * w1 + a.z * w2 + a.w * w3;
    }
  }
#pragma unroll
  for (int r = 0; r < 8; r++) red[r][t] = acc[r];
  __syncthreads();
  for (int idx = t; idx < 1024; idx += 256) {
    int r = idx >> 7, c = idx & 127;
    float val = red[r][c] + red[r][128 + c];
    out[(size_t)(row0 + r) * 128 + c] = val;
    As[idx] = val * al[c];
    As[4096 + idx] = val * ar[c];
  }
  __syncthreads();
  if (t < 8) {
    float s = 0.f;
    for (int c = 0; c < 128; c++) s += As[t * 128 + c];
    el[row0 + t] = s;
  } else if (t < 16) {
    int r = t - 8;
    float s = 0.f;
    for (int c = 0; c < 128; c++) s += As[4096 + r * 128 + c];
    er[row0 + r] = s;
  }
}

// ---------------- W pack: fragment-ordered fp16 tables ----------------
__global__ void pack_w2_kernel(const float* __restrict__ W2, const float* __restrict__ Wf,
                               bfu* __restrict__ w2h, bfu* __restrict__ wfh) {
  int i = blockIdx.x * 256 + threadIdx.x;  // 0..32767
  if (i >= 32768) return;
  const float* W = (i < 16384) ? W2 : Wf;
  bfu* dst = (i < 16384) ? w2h : wfh;
  int ii = i & 16383;
  int k = ii >> 7, n = ii & 127;
  bfu h = f2h(W[ii]);
  int kk = k >> 5, k5 = k & 31, quad = k5 >> 3, j = k5 & 7;
  int tt = n >> 4, m16 = n & 15;
  int pos = ((((kk * 8 + tt) * 4 + quad) * 16) + m16) * 8 + j;
  dst[pos] = h;
}

// generic K pack (used for W3, K=1024)
__global__ void pack_wk_kernel(const float* __restrict__ W, bfu* __restrict__ dst, int total) {
  int i = blockIdx.x * 256 + threadIdx.x;
  if (i >= total) return;
  int k = i >> 7, n = i & 127;
  bfu h = f2h(W[i]);
  int kk = k >> 5, k5 = k & 31, quad = k5 >> 3, j = k5 & 7;
  int tt = n >> 4, m16 = n & 15;
  int pos = ((((kk * 8 + tt) * 4 + quad) * 16) + m16) * 8 + j;
  dst[pos] = h;
}

// ---------------- fused aggregate + MFMA GEMM ----------------
// MODE 0: vocab-table aggregate (layer 1) -> LDS X1 -> MFMA w2h -> F fp16 + el/er logits
// MODE 1: F-gather aggregate (layer 2)   -> LDS X2 -> MFMA wfh -> Xf fp16 (bias+relu) + keyb
// adj entries are packed: src | (h[src] << 17)
template <int MODE>
__global__ __launch_bounds__(256) void agg_gemm_kernel(
    const bfu* __restrict__ Fsrc, const float* __restrict__ elA,
    const float* __restrict__ erA, const int* __restrict__ h,
    const int* __restrict__ row_ptr, const int* __restrict__ adj,
    const float* __restrict__ aggBias, const bfu* __restrict__ Wtab,
    const float* __restrict__ al, const float* __restrict__ ar,
    const float* __restrict__ gemmBias,
    bfu* __restrict__ outF,
    float* __restrict__ el_out, float* __restrict__ er_out,
    float* __restrict__ keyb) {
  __shared__ bfu Atile[128 * 128];  // 32 KB, chunk-XOR swizzled
  const int t = threadIdx.x;
  const int l = t & 31;
  const int gb = t & 32;
  const int grp = t >> 5;
  const int c0 = l * 4;
  const int blockbase = blockIdx.x * 128;
  float4 bv = *(const float4*)&aggBias[c0];

  // ---- phase 1: aggregate 128 dst rows into LDS ----
  for (int iter = 0; iter < 16; ++iter) {
    const int dl = iter * 8 + grp;    // local row 0..127
    const int d = blockbase + dl;
    int beg = row_ptr[d];
    int n = row_ptr[d + 1] - beg;
    float4 acc = make_float4(0.f, 0.f, 0.f, 0.f);
    if (n > 0) {
      float er_d = (MODE == 0) ? erA[h[d]] : erA[d];
      if (n <= 32) {
        int idx = 0; float sc = -INFINITY;
        if (l < n) {
          int a = adj[beg + l];
          idx = (MODE == 0) ? (a >> 17) : (a & SRCMASK);
          float v = elA[idx] + er_d;
          sc = v > 0.f ? v : 0.2f * v;
        }
        float m = sc;
#pragma unroll
        for (int off = 16; off; off >>= 1) m = fmaxf(m, __shfl_xor(m, off));
        float ex = (l < n) ? expf(sc - m) : 0.f;
        float s = ex;
#pragma unroll
        for (int off = 16; off; off >>= 1) s += __shfl_xor(s, off);
        float wt = ex / s;
        for (int j = 0; j < n; j += 4) {
          int   s0 = __shfl(idx, gb + j);
          float w0 = __shfl(wt, gb + j);
          int   j1 = (j + 1 < n) ? j + 1 : j;
          int   s1 = __shfl(idx, gb + j1); float w1 = (j + 1 < n) ? __shfl(wt, gb + j1) : 0.f;
          int   j2 = (j + 2 < n) ? j + 2 : j;
          int   s2 = __shfl(idx, gb + j2); float w2 = (j + 2 < n) ? __shfl(wt, gb + j2) : 0.f;
          int   j3 = (j + 3 < n) ? j + 3 : j;
          int   s3 = __shfl(idx, gb + j3); float w3 = (j + 3 < n) ? __shfl(wt, gb + j3) : 0.f;
          ushort4 f0 = *(const ushort4*)&Fsrc[(size_t)s0 * 128 + c0];
          ushort4 f1 = *(const ushort4*)&Fsrc[(size_t)s1 * 128 + c0];
          ushort4 f2 = *(const ushort4*)&Fsrc[(size_t)s2 * 128 + c0];
          ushort4 f3 = *(const ushort4*)&Fsrc[(size_t)s3 * 128 + c0];
          acc.x += w0 * h2f(f0.x) + w1 * h2f(f1.x) + w2 * h2f(f2.x) + w3 * h2f(f3.x);
          acc.y += w0 * h2f(f0.y) + w1 * h2f(f1.y) + w2 * h2f(f2.y) + w3 * h2f(f3.y);
          acc.z += w0 * h2f(f0.z) + w1 * h2f(f1.z) + w2 * h2f(f2.z) + w3 * h2f(f3.z);
          acc.w += w0 * h2f(f0.w) + w1 * h2f(f1.w) + w2 * h2f(f2.w) + w3 * h2f(f3.w);
        }
      } else {
        float lm = -INFINITY;
        for (int e = l; e < n; e += 32) {
          int a = adj[beg + e];
          int idx = (MODE == 0) ? (a >> 17) : (a & SRCMASK);
          float v = elA[idx] + er_d;
          v = v > 0.f ? v : 0.2f * v;
          lm = fmaxf(lm, v);
        }
#pragma unroll
        for (int off = 16; off; off >>= 1) lm = fmaxf(lm, __shfl_xor(lm, off));
        float ls = 0.f;
        for (int e = l; e < n; e += 32) {
          int a = adj[beg + e];
          int idx = (MODE == 0) ? (a >> 17) : (a & SRCMASK);
          float v = elA[idx] + er_d;
          v = v > 0.f ? v : 0.2f * v;
          ls += expf(v - lm);
        }
#pragma unroll
        for (int off = 16; off; off >>= 1) ls += __shfl_xor(ls, off);
        for (int base = 0; base < n; base += 32) {
          int e = base + l;
          int idx = 0; float wt = 0.f;
          if (e < n) {
            int a = adj[beg + e];
            idx = (MODE == 0) ? (a >> 17) : (a & SRCMASK);
            float v = elA[idx] + er_d;
            v = v > 0.f ? v : 0.2f * v;
            wt = expf(v - lm) / ls;
          }
          int cnt = min(32, n - base);
          for (int j = 0; j < cnt; ++j) {
            int s0 = __shfl(idx, gb + j);
            float w0 = __shfl(wt, gb + j);
            ushort4 f0 = *(const ushort4*)&Fsrc[(size_t)s0 * 128 + c0];
            acc.x += w0 * h2f(f0.x);
            acc.y += w0 * h2f(f0.y);
            acc.z += w0 * h2f(f0.z);
            acc.w += w0 * h2f(f0.w);
          }
        }
      }
    }
    // bias + relu, store fp16 into LDS (chunk-XOR swizzle)
    ushort4 o;
    o.x = f2h(fmaxf(acc.x + bv.x, 0.f));
    o.y = f2h(fmaxf(acc.y + bv.y, 0.f));
    o.z = f2h(fmaxf(acc.z + bv.z, 0.f));
    o.w = f2h(fmaxf(acc.w + bv.w, 0.f));
    int chunk = l >> 1;
    int off = dl * 256 + (((chunk ^ (dl & 15)) << 4)) + ((l & 1) << 3);
    *(ushort4*)((char*)Atile + off) = o;
  }
  __syncthreads();

  // ---- phase 2: MFMA over LDS A-tile ----
  const int lane = t & 63, wv_ = t >> 6;
  const int m16 = lane & 15, quad = lane >> 4;
  f32x4 acc2[2][8];
#pragma unroll
  for (int rg = 0; rg < 2; rg++)
#pragma unroll
    for (int i = 0; i < 8; i++) acc2[rg][i] = (f32x4){0.f, 0.f, 0.f, 0.f};
#pragma unroll
  for (int kk = 0; kk < 4; kk++) {
    int cb = kk * 4 + quad;
    int r0 = wv_ * 32 + m16;
    int r1 = r0 + 16;
    int a0 = r0 * 256 + ((cb ^ (r0 & 15)) << 4);
    int a1 = r1 * 256 + ((cb ^ (r1 & 15)) << 4);
    f16x8 ahi0 = *(const f16x8*)((char*)Atile + a0);
    f16x8 ahi1 = *(const f16x8*)((char*)Atile + a1);
#pragma unroll
    for (int tt = 0; tt < 8; tt++) {
      int pos = ((((kk * 8 + tt) * 4 + quad) * 16) + m16) * 8;
      f16x8 bhi = *(const f16x8*)&Wtab[pos];
      acc2[0][tt] = __builtin_amdgcn_mfma_f32_16x16x32_f16(ahi0, bhi, acc2[0][tt], 0, 0, 0);
      acc2[1][tt] = __builtin_amdgcn_mfma_f32_16x16x32_f16(ahi1, bhi, acc2[1][tt], 0, 0, 0);
    }
  }
  // ---- epilogue ----
#pragma unroll
  for (int rg = 0; rg < 2; rg++) {
    const int rb = blockbase + wv_ * 32 + rg * 16;
    if constexpr (MODE == 0) {
      float pl[4] = {0.f, 0.f, 0.f, 0.f}, pr[4] = {0.f, 0.f, 0.f, 0.f};
#pragma unroll
      for (int tt = 0; tt < 8; tt++) {
        int col = tt * 16 + m16;
        float alv = al[col], arv = ar[col];
#pragma unroll
        for (int r = 0; r < 4; r++) {
          float v = acc2[rg][tt][r];
          outF[(size_t)(rb + quad * 4 + r) * 128 + col] = f2h(v);
          pl[r] += v * alv;
          pr[r] += v * arv;
        }
      }
#pragma unroll
      for (int r = 0; r < 4; r++) {
        float a0 = pl[r], a1 = pr[r];
#pragma unroll
        for (int off = 1; off < 16; off <<= 1) {
          a0 += __shfl_xor(a0, off);
          a1 += __shfl_xor(a1, off);
        }
        if (m16 == 0) {
          el_out[rb + quad * 4 + r] = a0;
          er_out[rb + quad * 4 + r] = a1;
        }
      }
    } else {
      float pm[4] = {-INFINITY, -INFINITY, -INFINITY, -INFINITY};
#pragma unroll
      for (int tt = 0; tt < 8; tt++) {
        int col = tt * 16 + m16;
        float bvv = gemmBias[col];
#pragma unroll
        for (int r = 0; r < 4; r++) {
          float v = fmaxf(acc2[rg][tt][r] + bvv, 0.f);
          outF[(size_t)(rb + quad * 4 + r) * 128 + col] = f2h(v);
          pm[r] = fmaxf(pm[r], v);
        }
      }
#pragma unroll
      for (int r = 0; r < 4; r++) {
        float a0 = pm[r];
#pragma unroll
        for (int off = 1; off < 16; off <<= 1) a0 = fmaxf(a0, __shfl_xor(a0, off));
        if (m16 == 0) keyb[rb + quad * 4 + r] = a0;
      }
    }
  }
}

// ---------------- MFMA outer-GAT GEMM: f3 = xp(fp16)[2048,1024] @ W3tab, + logits ----------------
__global__ __launch_bounds__(256) void mfma_gemm1024_kernel(
    const bfu* __restrict__ A, const bfu* __restrict__ Wtab,
    float* __restrict__ out, const float* __restrict__ al,
    const float* __restrict__ ar, float* __restrict__ el,
    float* __restrict__ er) {
  const int t = threadIdx.x;
  const int lane = t & 63, wv_ = t >> 6;
  const int m16 = lane & 15, quad = lane >> 4;
  const int rowbase = blockIdx.x * 128 + wv_ * 32;
  const bfu* brow0 = A + (size_t)(rowbase + m16) * 1024;
  const bfu* brow1 = A + (size_t)(rowbase + 16 + m16) * 1024;
  f32x4 acc[2][8];
#pragma unroll
  for (int rg = 0; rg < 2; rg++)
#pragma unroll
    for (int i = 0; i < 8; i++) acc[rg][i] = (f32x4){0.f, 0.f, 0.f, 0.f};
  for (int kk = 0; kk < 32; kk++) {
    int k0 = kk * 32 + quad * 8;
    f16x8 ahi0 = *(const f16x8*)(brow0 + k0);
    f16x8 ahi1 = *(const f16x8*)(brow1 + k0);
#pragma unroll
    for (int tt = 0; tt < 8; tt++) {
      int pos = ((((kk * 8 + tt) * 4 + quad) * 16) + m16) * 8;
      f16x8 bhi = *(const f16x8*)&Wtab[pos];
      acc[0][tt] = __builtin_amdgcn_mfma_f32_16x16x32_f16(ahi0, bhi, acc[0][tt], 0, 0, 0);
      acc[1][tt] = __builtin_amdgcn_mfma_f32_16x16x32_f16(ahi1, bhi, acc[1][tt], 0, 0, 0);
    }
  }
#pragma unroll
  for (int rg = 0; rg < 2; rg++) {
    const int rb = rowbase + rg * 16;
    float pl[4] = {0.f, 0.f, 0.f, 0.f}, pr[4] = {0.f, 0.f, 0.f, 0.f};
#pragma unroll
    for (int tt = 0; tt < 8; tt++) {
      int col = tt * 16 + m16;
      float alv = al[col], arv = ar[col];
#pragma unroll
      for (int r = 0; r < 4; r++) {
        float v = acc[rg][tt][r];
        out[(size_t)(rb + quad * 4 + r) * 128 + col] = v;
        pl[r] += v * alv;
        pr[r] += v * arv;
      }
    }
#pragma unroll
    for (int r = 0; r < 4; r++) {
      float a0 = pl[r], a1 = pr[r];
#pragma unroll
      for (int off = 1; off < 16; off <<= 1) {
        a0 += __shfl_xor(a0, off);
        a1 += __shfl_xor(a1, off);
      }
      if (m16 == 0) {
        el[rb + quad * 4 + r] = a0;
        er[rb + quad * 4 + r] = a1;
      }
    }
  }
}

// ---------------- attention logits (fallback path) ----------------
__global__ __launch_bounds__(64) void attn_logits_kernel(
    const float* __restrict__ f, const float* __restrict__ al,
    const float* __restrict__ ar, float* __restrict__ el,
    float* __restrict__ er) {
  int node = blockIdx.x, lane = threadIdx.x;
  float v1 = f[(size_t)node * 128 + lane];
  float v2 = f[(size_t)node * 128 + 64 + lane];
  float sl = v1 * al[lane] + v2 * al[64 + lane];
  float sr = v1 * ar[lane] + v2 * ar[64 + lane];
#pragma unroll
  for (int off = 32; off; off >>= 1) {
    sl += __shfl_down(sl, off);
    sr += __shfl_down(sr, off);
  }
  if (lane == 0) { el[node] = sl; er[node] = sr; }
}

// ---------------- CSR build ----------------
__global__ void hist_rank_kernel(const int* __restrict__ dst, int* __restrict__ cnt,
                                 int* __restrict__ rank, int nE) {
  int e = blockIdx.x * 256 + threadIdx.x;
  if (e < nE) rank[e] = atomicAdd(&cnt[dst[e]], 1);
}

__global__ __launch_bounds__(256) void scan_block_kernel(
    const int* __restrict__ cnt, int* __restrict__ excl, int* __restrict__ part) {
  __shared__ int s[256];
  int blk = blockIdx.x, tid = threadIdx.x;
  int base = blk * 1024 + tid * 4;
  int a0 = cnt[base], a1 = cnt[base + 1], a2 = cnt[base + 2], a3 = cnt[base + 3];
  int tsum = a0 + a1 + a2 + a3;
  s[tid] = tsum; __syncthreads();
  for (int off = 1; off < 256; off <<= 1) {
    int v = (tid >= off) ? s[tid - off] : 0;
    __syncthreads();
    s[tid] += v;
    __syncthreads();
  }
  int texcl = s[tid] - tsum;
  excl[base]     = texcl;
  excl[base + 1] = texcl + a0;
  excl[base + 2] = texcl + a0 + a1;
  excl[base + 3] = texcl + a0 + a1 + a2;
  if (tid == 255) part[blk] = s[255];
}

__global__ __launch_bounds__(128) void scan_part_kernel(int* __restrict__ part) {
  __shared__ int s[128];
  int tid = threadIdx.x;
  int orig = part[tid];
  s[tid] = orig; __syncthreads();
  for (int off = 1; off < 128; off <<= 1) {
    int v = (tid >= off) ? s[tid - off] : 0;
    __syncthreads();
    s[tid] += v;
    __syncthreads();
  }
  part[tid] = s[tid] - orig;
}

__global__ void scan_add_kernel(int* __restrict__ row_ptr, const int* __restrict__ part,
                                int n, int total) {
  int i = blockIdx.x * 256 + threadIdx.x;
  if (i < n) row_ptr[i] += part[i >> 10];
  if (i == 0) row_ptr[n] = total;
}

// single-block exclusive scan over 2048 counts (outer graph)
__global__ __launch_bounds__(256) void scan2048_kernel(const int* __restrict__ cnt,
                                                       int* __restrict__ rp, int total) {
  __shared__ int s[256];
  int t = threadIdx.x;
  int base = t * 8;
  int v[8];
  int tsum = 0;
#pragma unroll
  for (int i = 0; i < 8; i++) { v[i] = cnt[base + i]; tsum += v[i]; }
  s[t] = tsum; __syncthreads();
  for (int off = 1; off < 256; off <<= 1) {
    int x = (t >= off) ? s[t - off] : 0;
    __syncthreads();
    s[t] += x;
    __syncthreads();
  }
  int excl = s[t] - tsum;
#pragma unroll
  for (int i = 0; i < 8; i++) { rp[base + i] = excl; excl += v[i]; }
  if (t == 255) rp[2048] = total;
}

__global__ void scatter2_kernel(const int* __restrict__ dst, const int* __restrict__ src,
                                const int* __restrict__ row_ptr, const int* __restrict__ rank,
                                int* __restrict__ adj_src, int nE) {
  int e = blockIdx.x * 256 + threadIdx.x;
  if (e >= nE) return;
  adj_src[row_ptr[dst[e]] + rank[e]] = src[e];
}

// inner scatter with h packed into high bits: adj = src | (h[src] << 17)
__global__ void scatter2_pack_kernel(const int* __restrict__ dst, const int* __restrict__ src,
                                     const int* __restrict__ h,
                                     const int* __restrict__ row_ptr, const int* __restrict__ rank,
                                     int* __restrict__ adj_src, int nE) {
  int e = blockIdx.x * 256 + threadIdx.x;
  if (e >= nE) return;
  int s = src[e];
  adj_src[row_ptr[dst[e]] + rank[e]] = s | (h[s] << 17);
}

// ---------------- fused outer GAT aggregation (fp32 f3 gather) ----------------
__global__ __launch_bounds__(256) void gat_aggregate_outer_kernel(
    const float* __restrict__ F, const float* __restrict__ el,
    const float* __restrict__ er, const int* __restrict__ row_ptr,
    const int* __restrict__ adj_src,
    const float* __restrict__ bias, float* __restrict__ outG) {
  const int t = threadIdx.x;
  const int l = t & 31;
  const int gb = t & 32;
  const int d = blockIdx.x * 8 + (t >> 5);
  const int c0 = l * 4;
  int beg = row_ptr[d];
  int n = row_ptr[d + 1] - beg;
  float4 bv = *(const float4*)&bias[c0];
  if (n == 0) {
    float4 o;
    o.x = fmaxf(bv.x, 0.f); o.y = fmaxf(bv.y, 0.f);
    o.z = fmaxf(bv.z, 0.f); o.w = fmaxf(bv.w, 0.f);
    *(float4*)&outG[(size_t)d * 128 + c0] = o;
    return;
  }
  float er_d = er[d];
  float4 acc = make_float4(0.f, 0.f, 0.f, 0.f);
  if (n <= 32) {
    int sv = 0; float sc = -INFINITY;
    if (l < n) {
      sv = adj_src[beg + l];
      float v = el[sv] + er_d;
      sc = v > 0.f ? v : 0.2f * v;
    }
    float m = sc;
#pragma unroll
    for (int off = 16; off; off >>= 1) m = fmaxf(m, __shfl_xor(m, off));
    float ex = (l < n) ? expf(sc - m) : 0.f;
    float s = ex;
#pragma unroll
    for (int off = 16; off; off >>= 1) s += __shfl_xor(s, off);
    float wt = ex / s;
    for (int j = 0; j < n; ++j) {
      int   s0 = __shfl(sv, gb + j);
      float w0 = __shfl(wt, gb + j);
      float4 f0 = *(const float4*)&F[(size_t)s0 * 128 + c0];
      acc.x += w0 * f0.x; acc.y += w0 * f0.y;
      acc.z += w0 * f0.z; acc.w += w0 * f0.w;
    }
  } else {
    float lm = -INFINITY;
    for (int e = l; e < n; e += 32) {
      int sv = adj_src[beg + e];
      float v = el[sv] + er_d;
      v = v > 0.f ? v : 0.2f * v;
      lm = fmaxf(lm, v);
    }
#pragma unroll
    for (int off = 16; off; off >>= 1) lm = fmaxf(lm, __shfl_xor(lm, off));
    float ls = 0.f;
    for (int e = l; e < n; e += 32) {
      int sv = adj_src[beg + e];
      float v = el[sv] + er_d;
      v = v > 0.f ? v : 0.2f * v;
      ls += expf(v - lm);
    }
#pragma unroll
    for (int off = 16; off; off >>= 1) ls += __shfl_xor(ls, off);
    for (int base = 0; base < n; base += 32) {
      int e = base + l;
      int sv = 0; float wt = 0.f;
      if (e < n) {
        sv = adj_src[beg + e];
        float v = el[sv] + er_d;
        v = v > 0.f ? v : 0.2f * v;
        wt = expf(v - lm) / ls;
      }
      int cnt = min(32, n - base);
      for (int j = 0; j < cnt; ++j) {
        int s0 = __shfl(sv, gb + j);
        float w0 = __shfl(wt, gb + j);
        float4 f0 = *(const float4*)&F[(size_t)s0 * 128 + c0];
        acc.x += w0 * f0.x; acc.y += w0 * f0.y;
        acc.z += w0 * f0.z; acc.w += w0 * f0.w;
      }
    }
  }
  float4 o;
  o.x = fmaxf(acc.x + bv.x, 0.f);
  o.y = fmaxf(acc.y + bv.y, 0.f);
  o.z = fmaxf(acc.z + bv.z, 0.f);
  o.w = fmaxf(acc.w + bv.w, 0.f);
  *(float4*)&outG[(size_t)d * 128 + c0] = o;
}

// ---------------- atomic-path edge kernels (fallback only) ----------------
static __device__ __forceinline__ void atomicMaxF(float* addr, float v) {
  int iv = __float_as_int(v);
  if (iv >= 0) atomicMax((int*)addr, iv);
  else atomicMin((unsigned int*)addr, (unsigned int)iv);
}

static __device__ __forceinline__ float edge_score(const float* el, const float* er,
                                                   int sv, int dv) {
  float v = el[sv] + er[dv];
  return v > 0.f ? v : 0.2f * v;
}

__global__ void edge_max_kernel(const float* __restrict__ el,
                                const float* __restrict__ er,
                                const int* __restrict__ src,
                                const int* __restrict__ dst,
                                float* __restrict__ m, int nE) {
  int e = blockIdx.x * 256 + threadIdx.x;
  if (e >= nE) return;
  atomicMaxF(&m[dst[e]], edge_score(el, er, src[e], dst[e]));
}

__global__ void edge_expsum_kernel(const float* __restrict__ el,
                                   const float* __restrict__ er,
                                   const float* __restrict__ m,
                                   const int* __restrict__ src,
                                   const int* __restrict__ dst,
                                   float* __restrict__ s, int nE) {
  int e = blockIdx.x * 256 + threadIdx.x;
  if (e >= nE) return;
  int d = dst[e];
  atomicAdd(&s[d], expf(edge_score(el, er, src[e], d) - m[d]));
}

__global__ __launch_bounds__(128) void edge_aggregate_kernel(
    const float* __restrict__ f, const float* __restrict__ el,
    const float* __restrict__ er, const float* __restrict__ m,
    const float* __restrict__ s, const int* __restrict__ src,
    const int* __restrict__ dst, float* __restrict__ out, int nE) {
  int e = blockIdx.x;
  int d = threadIdx.x;
  int sv = src[e], dv = dst[e];
  float alpha = expf(edge_score(el, er, sv, dv) - m[dv]) / s[dv];
  atomicAdd(&out[(size_t)dv * 128 + d], alpha * f[(size_t)sv * 128 + d]);
}

__global__ void bias_relu_kernel(float* __restrict__ x,
                                 const float* __restrict__ b, int total) {
  int i = blockIdx.x * 256 + threadIdx.x;
  if (i >= total) return;
  x[i] = fmaxf(x[i] + b[i & 127], 0.f);
}

// ---------------- sort pooling ----------------
__global__ __launch_bounds__(64) void row_max_kernel(const float* __restrict__ x,
                                                     float* __restrict__ key) {
  int node = blockIdx.x, lane = threadIdx.x;
  float v = fmaxf(x[(size_t)node * 128 + lane], x[(size_t)node * 128 + 64 + lane]);
#pragma unroll
  for (int off = 32; off; off >>= 1) v = fmaxf(v, __shfl_down(v, off));
  if (lane == 0) key[node] = v;
}

__global__ __launch_bounds__(64) void select_topk_kernel(
    const float* __restrict__ key, int* __restrict__ sel) {
  __shared__ float keys[NPG];
  int g = blockIdx.x, t = threadIdx.x;
  keys[t] = key[(size_t)g * NPG + t];
  __syncthreads();
  float myk = keys[t];
  int rank = 0;
  for (int j = 0; j < NPG; ++j) {
    float kj = keys[j];
    rank += (kj > myk) || (kj == myk && j < t);
  }
  if (rank < KK) sel[g * KK + rank] = t;
}

// fused top-k select + 8-row bitonic sort -> fp16 xp (CSR path)
__global__ __launch_bounds__(1024) void topk_sort_kernel(
    const float* __restrict__ keyb, const bfu* __restrict__ xin,
    bfu* __restrict__ xp) {
  __shared__ float keys[NPG];
  __shared__ int sel_l[KK];
  __shared__ float v[1024];
  int g = blockIdx.x, t = threadIdx.x;
  if (t < NPG) keys[t] = keyb[(size_t)g * NPG + t];
  __syncthreads();
  if (t < NPG) {
    float myk = keys[t];
    int rank = 0;
    for (int j = 0; j < NPG; ++j) {
      float kj = keys[j];
      rank += (kj > myk) || (kj == myk && j < t);
    }
    if (rank < KK) sel_l[rank] = t;
  }
  __syncthreads();
  int r = t >> 7, c = t & 127;
  int node = sel_l[r];
  v[t] = h2f(xin[(size_t)(g * NPG + node) * 128 + c]);
  __syncthreads();
  for (int k = 2; k <= 128; k <<= 1) {
    for (int j = k >> 1; j > 0; j >>= 1) {
      int ixj = c ^ j;
      if (ixj > c) {
        float a = v[r * 128 + c], bb = v[r * 128 + ixj];
        bool asc = ((c & k) == 0);
        if (asc ? (a > bb) : (a < bb)) { v[r * 128 + c] = bb; v[r * 128 + ixj] = a; }
      }
      __syncthreads();
    }
  }
  xp[(size_t)g * 1024 + t] = f2h(v[t]);
}

template <int HF>
__global__ __launch_bounds__(128) void sort_rows_kernel(
    const void* __restrict__ xin, const int* __restrict__ sel,
    float* __restrict__ xp) {
  __shared__ float v[128];
  int b = blockIdx.x;
  int t = threadIdx.x;
  int g = b >> 3, r = b & 7;
  int node = sel[b];
  if (HF) v[t] = h2f(((const bfu*)xin)[(size_t)(g * NPG + node) * 128 + t]);
  else    v[t] = ((const float*)xin)[(size_t)(g * NPG + node) * 128 + t];
  __syncthreads();
  for (int k = 2; k <= 128; k <<= 1) {
    for (int j = k >> 1; j > 0; j >>= 1) {
      int ixj = t ^ j;
      if (ixj > t) {
        float a = v[t], bb = v[ixj];
        bool asc = ((t & k) == 0);
        if (asc ? (a > bb) : (a < bb)) { v[t] = bb; v[ixj] = a; }
      }
      __syncthreads();
    }
  }
  xp[(size_t)g * (KK * 128) + r * 128 + t] = v[t];
}

// ---------------- fused tail MLP ----------------
__global__ __launch_bounds__(128) void mlp_tail_kernel(
    const float* __restrict__ g3, const float* __restrict__ Wl,
    const float* __restrict__ bl, const float* __restrict__ Wl1,
    const float* __restrict__ bl1, const float* __restrict__ Wc,
    const float* __restrict__ bc, float* __restrict__ out) {
  __shared__ float buf[128];
  __shared__ float r0[128], r1[128];
  int g = blockIdx.x, t = threadIdx.x;
  buf[t] = g3[(size_t)g * 128 + t];
  __syncthreads();
  float a = 0.f;
  for (int k = 0; k < 128; k++) a += buf[k] * Wl[k * 128 + t];
  float t1 = fmaxf(a + bl[t], 0.f);
  __syncthreads();
  buf[t] = t1;
  __syncthreads();
  a = 0.f;
  for (int k = 0; k < 128; k++) a += buf[k] * Wl1[k * 128 + t];
  float t2 = fmaxf(a + bl1[t], 0.f);
  r0[t] = t2 * Wc[t * 2 + 0];
  r1[t] = t2 * Wc[t * 2 + 1];
  __syncthreads();
  for (int off = 64; off; off >>= 1) {
    if (t < off) { r0[t] += r0[t + off]; r1[t] += r1[t + off]; }
    __syncthreads();
  }
  if (t == 0) {
    out[g * 2 + 0] = r0[0] + bc[0];
    out[g * 2 + 1] = r1[0] + bc[1];
  }
}

// ---------------- launcher ----------------
extern "C" void kernel_launch(void* const* d_in, const int* in_sizes, int n_in,
                              void* d_out, int out_size, void* d_ws, size_t ws_size,
                              hipStream_t stream) {
  const size_t BASE_FLOATS = (size_t)NN * DD * 2 + (size_t)NN * 4;  // X,F,el,er,mx,sm
  const size_t CSR_INTS = (size_t)(NN + 1) + NN + EE + 128;          // row_ptr,cursor,adj,part
  if (ws_size < BASE_FLOATS * sizeof(float)) {
    hipMemsetAsync(d_out, 0, (size_t)out_size * sizeof(float), stream);
    return;
  }
  const bool use_csr = ws_size >= BASE_FLOATS * sizeof(float) + CSR_INTS * sizeof(int);

  const int* h      = (const int*)d_in[0];
  const int* g_src  = (const int*)d_in[1];
  const int* g_dst  = (const int*)d_in[2];
  const int* fg_src = (const int*)d_in[3];
  const int* fg_dst = (const int*)d_in[4];
  const float* temb = (const float*)d_in[5];
  const float* W1 = (const float*)d_in[6];
  const float* al1 = (const float*)d_in[7];
  const float* ar1 = (const float*)d_in[8];
  const float* b1 = (const float*)d_in[9];
  const float* W2 = (const float*)d_in[10];
  const float* al2 = (const float*)d_in[11];
  const float* ar2 = (const float*)d_in[12];
  const float* b2 = (const float*)d_in[13];
  const float* W3 = (const float*)d_in[14];
  const float* al3 = (const float*)d_in[15];
  const float* ar3 = (const float*)d_in[16];
  const float* b3 = (const float*)d_in[17];
  const float* Wf = (const float*)d_in[18];
  const float* bfv = (const float*)d_in[19];
  const float* Wl = (const float*)d_in[20];
  const float* bl = (const float*)d_in[21];
  const float* Wl1 = (const float*)d_in[22];
  const float* bl1 = (const float*)d_in[23];
  const float* Wc = (const float*)d_in[24];
  const float* bc = (const float*)d_in[25];
  float* out = (float*)d_out;

  // ---- workspace layout ----
  float* ws = (float*)d_ws;
  float* X  = ws;                    // CSR: Xf fp16 in first half; keyb2 in upper half
  float* F  = X + (size_t)NN * DD;   // CSR: F fp16, later xp fp16 / f3
  float* el = F + (size_t)NN * DD;
  float* er = el + NN;
  float* mx = er + NN;
  float* sm = mx + NN;
  int* row_ptr = (int*)(sm + NN);
  int* cursor  = row_ptr + NN + 1;
  int* adj_src = cursor + NN;
  int* part    = adj_src + EE;
  // rank buffer aliases X (X first written after CSR build):
  int* rankb = (int*)X;
  // packed W tables + vocab tables live in mx/sm scratch:
  bfu* w2h = (bfu*)mx;                      // 16384
  bfu* wfh = w2h + 16384;                   // 16384
  bfu* fvh = wfh + 16384;                   // VOCAB*128
  float* elv = (float*)(fvh + VOCAB * 128 + 128);
  float* erv = elv + VOCAB;
  bfu* w3h = (bfu*)(erv + VOCAB + 2);       // 131072 entries (256 KB)
  // keyb for CSR path: upper half of X region (Xf fp16 uses first NN*DD/2 floats)
  float* keyb2 = X + (size_t)12 * 1024 * 1024;
  // outer-graph CSR aliases X start (Xf dead after topk_sort):
  int* ocnt  = (int*)X;               // 2048
  int* orp   = ocnt + 2048;           // 2049
  int* orank = orp + 2080;            // EFN
  int* oadj  = orank + EFN;           // EFN
  // carved from F once F is dead:
  float* xp   = F;                    // CSR: fp16 xp (4 MB); fallback: fp32
  float* f3   = F + 2097152;
  float* g3   = f3 + (size_t)GG * DD;
  float* t1   = g3 + (size_t)GG * DD;
  float* t2   = t1 + (size_t)GG * DD;
  float* keyb = t2 + (size_t)GG * DD; // fallback-path keyb
  int*   sel  = (int*)(keyb + NN);

  const int totalND = NN * DD;

  if (use_csr) {
    bfu* Fb  = (bfu*)F;
    bfu* Xb  = (bfu*)X;
    bfu* xph = (bfu*)xp;
    // ---- inner CSR (h packed into adj high bits) ----
    zero_int_kernel<<<NN / 256, 256, 0, stream>>>(cursor, NN);
    hist_rank_kernel<<<EE / 256, 256, 0, stream>>>(g_dst, cursor, rankb, EE);
    scan_block_kernel<<<NN / 1024, 256, 0, stream>>>(cursor, row_ptr, part);
    scan_part_kernel<<<1, 128, 0, stream>>>(part);
    scan_add_kernel<<<(NN + 255) / 256, 256, 0, stream>>>(row_ptr, part, NN, EE);
    scatter2_pack_kernel<<<EE / 256, 256, 0, stream>>>(g_dst, g_src, h, row_ptr, rankb, adj_src, EE);

    pack_w2_kernel<<<128, 256, 0, stream>>>(W2, Wf, w2h, wfh);
    pack_wk_kernel<<<512, 256, 0, stream>>>(W3, w3h, 131072);
    vocab_l1_kernel<<<VOCAB, 128, 0, stream>>>(temb, W1, al1, ar1, fvh, elv, erv);

    // fusion A: vocab aggregate (layer 1) + W2 GEMM -> F fp16 + el/er
    agg_gemm_kernel<0><<<NN / 128, 256, 0, stream>>>(
        fvh, elv, erv, h, row_ptr, adj_src, b1, w2h, al2, ar2, nullptr,
        Fb, el, er, nullptr);

    // fusion B: F-gather aggregate (layer 2) + Wf GEMM (bias+relu) -> Xf fp16 + keyb2
    agg_gemm_kernel<1><<<NN / 128, 256, 0, stream>>>(
        Fb, el, er, nullptr, row_ptr, adj_src, b2, wfh, nullptr, nullptr, bfv,
        Xb, nullptr, nullptr, keyb2);

    // fused sort pooling -> xp (fp16)
    topk_sort_kernel<<<GG, 1024, 0, stream>>>(keyb2, Xb, xph);

    // outer CSR build (multi-block; X start dead now)
    zero_int_kernel<<<GG / 256, 256, 0, stream>>>(ocnt, GG);
    hist_rank_kernel<<<EFN / 256, 256, 0, stream>>>(fg_dst, ocnt, orank, EFN);
    scan2048_kernel<<<1, 256, 0, stream>>>(ocnt, orp, EFN);
    scatter2_kernel<<<EFN / 256, 256, 0, stream>>>(fg_dst, fg_src, orp, orank, oadj, EFN);

    // outer GAT: MFMA GEMM (+fused logits) + fused aggregate
    mfma_gemm1024_kernel<<<GG / 128, 256, 0, stream>>>(xph, w3h, f3, al3, ar3, el, er);
    gat_aggregate_outer_kernel<<<GG / 8, 256, 0, stream>>>(f3, el, er, orp, oadj, b3, g3);

    // fused tail
    mlp_tail_kernel<<<GG, 128, 0, stream>>>(g3, Wl, bl, Wl1, bl1, Wc, bc, out);
  } else {
    embed_relu_kernel<<<totalND / 256, 256, 0, stream>>>(temb, h, X, totalND);
    auto gat_inner = [&](const float* W, const float* al, const float* ar, const float* bb) {
      gemm_kernel<DD, 8><<<NN / 8, 128, 0, stream>>>(X, W, nullptr, F, 0);
      attn_logits_kernel<<<NN, 64, 0, stream>>>(F, al, ar, el, er);
      init_softmax_kernel<<<(NN + 255) / 256, 256, 0, stream>>>(mx, sm, NN);
      fill_f32_kernel<<<totalND / 256, 256, 0, stream>>>(X, 0.f, totalND);
      edge_max_kernel<<<(EE + 255) / 256, 256, 0, stream>>>(el, er, g_src, g_dst, mx, EE);
      edge_expsum_kernel<<<(EE + 255) / 256, 256, 0, stream>>>(el, er, mx, g_src, g_dst, sm, EE);
      edge_aggregate_kernel<<<EE, 128, 0, stream>>>(F, el, er, mx, sm, g_src, g_dst, X, EE);
      bias_relu_kernel<<<totalND / 256, 256, 0, stream>>>(X, bb, totalND);
    };
    gat_inner(W1, al1, ar1, b1);
    gat_inner(W2, al2, ar2, b2);
    gemm_kernel<DD, 8><<<NN / 8, 128, 0, stream>>>(X, Wf, bfv, X, 1);
    row_max_kernel<<<NN, 64, 0, stream>>>(X, keyb);

    select_topk_kernel<<<GG, 64, 0, stream>>>(keyb, sel);
    sort_rows_kernel<0><<<GG * KK, 128, 0, stream>>>(X, sel, xp);

    gemm1024_kernel<<<GG / 8, 256, 0, stream>>>(xp, W3, f3, al3, ar3, el, er);
    init_softmax_kernel<<<(GG + 255) / 256, 256, 0, stream>>>(mx, sm, GG);
    fill_f32_kernel<<<(GG * DD + 255) / 256, 256, 0, stream>>>(g3, 0.f, GG * DD);
    edge_max_kernel<<<(EFN + 255) / 256, 256, 0, stream>>>(el, er, fg_src, fg_dst, mx, EFN);
    edge_expsum_kernel<<<(EFN + 255) / 256, 256, 0, stream>>>(el, er, mx, fg_src, fg_dst, sm, EFN);
    edge_aggregate_kernel<<<EFN, 128, 0, stream>>>(f3, el, er, mx, sm, fg_src, fg_dst, g3, EFN);
    bias_relu_kernel<<<(GG * DD + 255) / 256, 256, 0, stream>>>(g3, b3, GG * DD);
    mlp_tail_kernel<<<GG, 128, 0, stream>>>(g3, Wl, bl, Wl1, bl1, Wc, bc, out);
  }
}

// Round 9
// 438.315 us; speedup vs baseline: 1.1233x; 1.1233x over previous
//
#include <hip/hip_runtime.h>
#include <math.h>

#define NN   131072   // total inner nodes
#define GG   2048     // graphs
#define NPG  64       // nodes per graph
#define EE   1048576  // inner edges
#define EFN  32768    // outer edges
#define DD   128      // feature dim
#define KK   8        // sortpool k
#define VOCAB 150
#define SRCMASK 0x1FFFF   // NN = 2^17

typedef unsigned short bfu;  // raw 16-bit float bits (fp16 on CSR path)
typedef _Float16 f16x8 __attribute__((ext_vector_type(8)));
typedef float f32x4 __attribute__((ext_vector_type(4)));

static __device__ __forceinline__ bfu f2h(float f) {  // RNE f32 -> fp16 bits
  _Float16 h = (_Float16)f;
  bfu u;
  __builtin_memcpy(&u, &h, 2);
  return u;
}
static __device__ __forceinline__ float h2f(bfu b) {
  _Float16 h;
  __builtin_memcpy(&h, &b, 2);
  return (float)h;
}

// ---------------- utility ----------------
__global__ void fill_f32_kernel(float* __restrict__ p, float v, int nElems) {
  int i = blockIdx.x * 256 + threadIdx.x;
  if (i < nElems) p[i] = v;
}

__global__ void zero_int_kernel(int* __restrict__ p, int nElems) {
  int i = blockIdx.x * 256 + threadIdx.x;
  if (i < nElems) p[i] = 0;
}

__global__ void init_softmax_kernel(float* __restrict__ mx, float* __restrict__ sm, int nElems) {
  int i = blockIdx.x * 256 + threadIdx.x;
  if (i < nElems) { mx[i] = -INFINITY; sm[i] = 0.f; }
}

// x[i] = relu(token_emb[h[node]][d])   (fallback path only)
__global__ void embed_relu_kernel(const float* __restrict__ temb,
                                  const int* __restrict__ h,
                                  float* __restrict__ x, int total) {
  int i = blockIdx.x * 256 + threadIdx.x;
  if (i >= total) return;
  int node = i >> 7, d = i & 127;
  x[i] = fmaxf(temb[h[node] * DD + d], 0.f);
}

// ---------------- small / generic GEMM (fallback) ----------------
template <int KD, int ROWS>
__global__ __launch_bounds__(128) void gemm_kernel(
    const float* __restrict__ A, const float* __restrict__ W,
    const float* __restrict__ bias, float* __restrict__ out,
    int relu_flag) {
  __shared__ float As[ROWS * KD];
  const int row0 = blockIdx.x * ROWS;
  const int tid = threadIdx.x;
  for (int i = tid; i < ROWS * KD; i += 128) As[i] = A[(size_t)row0 * KD + i];
  __syncthreads();
  float acc[ROWS];
#pragma unroll
  for (int r = 0; r < ROWS; r++) acc[r] = 0.f;
  for (int k = 0; k < KD; k++) {
    float w = W[k * 128 + tid];
#pragma unroll
    for (int r = 0; r < ROWS; r++) acc[r] += As[r * KD + k] * w;
  }
  float b = bias ? bias[tid] : 0.f;
#pragma unroll
  for (int r = 0; r < ROWS; r++) {
    float v = acc[r] + b;
    if (relu_flag) v = fmaxf(v, 0.f);
    out[(size_t)(row0 + r) * 128 + tid] = v;
  }
}

// ---------------- vocab layer-1 table: fv = relu(temb) @ W1, logits ----------------
__global__ __launch_bounds__(128) void vocab_l1_kernel(
    const float* __restrict__ temb, const float* __restrict__ W1,
    const float* __restrict__ al1, const float* __restrict__ ar1,
    bfu* __restrict__ fvh, float* __restrict__ elv, float* __restrict__ erv) {
  __shared__ float xs[128];
  __shared__ float rl[128], rr[128];
  int v = blockIdx.x, t = threadIdx.x;
  xs[t] = fmaxf(temb[v * 128 + t], 0.f);
  __syncthreads();
  float acc = 0.f;
  for (int k = 0; k < 128; k++) acc += xs[k] * W1[k * 128 + t];
  fvh[v * 128 + t] = f2h(acc);
  rl[t] = acc * al1[t];
  rr[t] = acc * ar1[t];
  __syncthreads();
  for (int off = 64; off; off >>= 1) {
    if (t < off) { rl[t] += rl[t + off]; rr[t] += rr[t + off]; }
    __syncthreads();
  }
  if (t == 0) { elv[v] = rl[0]; erv[v] = rr[0]; }
}

// ---------------- outer-GAT GEMM + fused logits (fallback path) ----------------
__global__ __launch_bounds__(256) void gemm1024_kernel(
    const float* __restrict__ A, const float* __restrict__ W,
    float* __restrict__ out,
    const float* __restrict__ al, const float* __restrict__ ar,
    float* __restrict__ el, float* __restrict__ er) {
  __shared__ float As[8 * 1024];
  __shared__ float red[8][256];
  const int t = threadIdx.x;
  const int row0 = blockIdx.x * 8;
  for (int idx = t; idx < 8 * 256; idx += 256) {
    int r = idx >> 8, c4 = (idx & 255) << 2;
    *(float4*)&As[r * 1024 + c4] = *(const float4*)(A + (size_t)(row0 + r) * 1024 + c4);
  }
  __syncthreads();
  const int col = t & 127, kh = t >> 7;
  const int k0 = kh * 512;
  float acc[8];
#pragma unroll
  for (int r = 0; r < 8; r++) acc[r] = 0.f;
  for (int k = k0; k < k0 + 512; k += 4) {
    float w0 = W[(size_t)(k + 0) * 128 + col];
    float w1 = W[(size_t)(k + 1) * 128 + col];
    float w2 = W[(size_t)(k + 2) * 128 + col];
    float w3 = W[(size_t)(k + 3) * 128 + col];
#pragma unroll
    for (int r = 0; r < 8; r++) {
      float4 a = *(const float4*)&As[r * 1024 + k];
      acc[r] += a.x * w0 + a.y * w1 + a.z * w2 + a.w * w3;
    }
  }
#pragma unroll
  for (int r = 0; r < 8; r++) red[r][t] = acc[r];
  __syncthreads();
  for (int idx = t; idx < 1024; idx += 256) {
    int r = idx >> 7, c = idx & 127;
    float val = red[r][c] + red[r][128 + c];
    out[(size_t)(row0 + r) * 128 + c] = val;
    As[idx] = val * al[c];
    As[4096 + idx] = val * ar[c];
  }
  __syncthreads();
  if (t < 8) {
    float s = 0.f;
    for (int c = 0; c < 128; c++) s += As[t * 128 + c];
    el[row0 + t] = s;
  } else if (t < 16) {
    int r = t - 8;
    float s = 0.f;
    for (int c = 0; c < 128; c++) s += As[4096 + r * 128 + c];
    er[row0 + r] = s;
  }
}

// ---------------- W pack: fragment-ordered fp16 tables ----------------
__global__ void pack_w2_kernel(const float* __restrict__ W2, const float* __restrict__ Wf,
                               bfu* __restrict__ w2h, bfu* __restrict__ wfh) {
  int i = blockIdx.x * 256 + threadIdx.x;  // 0..32767
  if (i >= 32768) return;
  const float* W = (i < 16384) ? W2 : Wf;
  bfu* dst = (i < 16384) ? w2h : wfh;
  int ii = i & 16383;
  int k = ii >> 7, n = ii & 127;
  bfu h = f2h(W[ii]);
  int kk = k >> 5, k5 = k & 31, quad = k5 >> 3, j = k5 & 7;
  int tt = n >> 4, m16 = n & 15;
  int pos = ((((kk * 8 + tt) * 4 + quad) * 16) + m16) * 8 + j;
  dst[pos] = h;
}

// generic K pack (used for W3, K=1024)
__global__ void pack_wk_kernel(const float* __restrict__ W, bfu* __restrict__ dst, int total) {
  int i = blockIdx.x * 256 + threadIdx.x;
  if (i >= total) return;
  int k = i >> 7, n = i & 127;
  bfu h = f2h(W[i]);
  int kk = k >> 5, k5 = k & 31, quad = k5 >> 3, j = k5 & 7;
  int tt = n >> 4, m16 = n & 15;
  int pos = ((((kk * 8 + tt) * 4 + quad) * 16) + m16) * 8 + j;
  dst[pos] = h;
}

// ---------------- MFMA GEMM (LDS-free, 32 rows/wave), fp16 A, hi-only W ----------------
// EPI: 1 = fp16 F out + attention logits,  2 = fp16 out in-place + fp32 row-max key
template <int EPI>
__global__ __launch_bounds__(256) void mfma_gemm(
    const bfu* __restrict__ A, const bfu* __restrict__ WfHi,
    const float* __restrict__ bias, bfu* __restrict__ outF,
    const float* __restrict__ al, const float* __restrict__ ar,
    float* __restrict__ el, float* __restrict__ er,
    float* __restrict__ keyb) {
  const int t = threadIdx.x;
  const int lane = t & 63, wv_ = t >> 6;
  const int m16 = lane & 15, quad = lane >> 4;
  const int rowbase = blockIdx.x * 128 + wv_ * 32;
  const bfu* brow0 = A + (size_t)(rowbase + m16) * 128;
  const bfu* brow1 = A + (size_t)(rowbase + 16 + m16) * 128;
  f32x4 acc[2][8];
#pragma unroll
  for (int rg = 0; rg < 2; rg++)
#pragma unroll
    for (int i = 0; i < 8; i++) acc[rg][i] = (f32x4){0.f, 0.f, 0.f, 0.f};
#pragma unroll
  for (int kk = 0; kk < 4; kk++) {
    int k0 = kk * 32 + quad * 8;
    f16x8 ahi0 = *(const f16x8*)(brow0 + k0);
    f16x8 ahi1 = *(const f16x8*)(brow1 + k0);
#pragma unroll
    for (int tt = 0; tt < 8; tt++) {
      int pos = ((((kk * 8 + tt) * 4 + quad) * 16) + m16) * 8;
      f16x8 bhi = *(const f16x8*)&WfHi[pos];
      acc[0][tt] = __builtin_amdgcn_mfma_f32_16x16x32_f16(ahi0, bhi, acc[0][tt], 0, 0, 0);
      acc[1][tt] = __builtin_amdgcn_mfma_f32_16x16x32_f16(ahi1, bhi, acc[1][tt], 0, 0, 0);
    }
  }
#pragma unroll
  for (int rg = 0; rg < 2; rg++) {
    const int rb = rowbase + rg * 16;
    if constexpr (EPI == 1) {
      float pl[4] = {0.f, 0.f, 0.f, 0.f}, pr[4] = {0.f, 0.f, 0.f, 0.f};
#pragma unroll
      for (int tt = 0; tt < 8; tt++) {
        int col = tt * 16 + m16;
        float alv = al[col], arv = ar[col];
#pragma unroll
        for (int r = 0; r < 4; r++) {
          float v = acc[rg][tt][r];
          outF[(size_t)(rb + quad * 4 + r) * 128 + col] = f2h(v);
          pl[r] += v * alv;
          pr[r] += v * arv;
        }
      }
#pragma unroll
      for (int r = 0; r < 4; r++) {
        float a0 = pl[r], a1 = pr[r];
#pragma unroll
        for (int off = 1; off < 16; off <<= 1) {
          a0 += __shfl_xor(a0, off);
          a1 += __shfl_xor(a1, off);
        }
        if (m16 == 0) {
          el[rb + quad * 4 + r] = a0;
          er[rb + quad * 4 + r] = a1;
        }
      }
    } else {
      float pm[4] = {-INFINITY, -INFINITY, -INFINITY, -INFINITY};
#pragma unroll
      for (int tt = 0; tt < 8; tt++) {
        int col = tt * 16 + m16;
        float bv = bias[col];
#pragma unroll
        for (int r = 0; r < 4; r++) {
          float v = fmaxf(acc[rg][tt][r] + bv, 0.f);
          outF[(size_t)(rb + quad * 4 + r) * 128 + col] = f2h(v);
          pm[r] = fmaxf(pm[r], v);
        }
      }
#pragma unroll
      for (int r = 0; r < 4; r++) {
        float a0 = pm[r];
#pragma unroll
        for (int off = 1; off < 16; off <<= 1) a0 = fmaxf(a0, __shfl_xor(a0, off));
        if (m16 == 0) keyb[rb + quad * 4 + r] = a0;
      }
    }
  }
}

// ---------------- MFMA outer-GAT GEMM: f3 = xp(fp16)[2048,1024] @ W3tab, + logits ----------------
__global__ __launch_bounds__(256) void mfma_gemm1024_kernel(
    const bfu* __restrict__ A, const bfu* __restrict__ Wtab,
    float* __restrict__ out, const float* __restrict__ al,
    const float* __restrict__ ar, float* __restrict__ el,
    float* __restrict__ er) {
  const int t = threadIdx.x;
  const int lane = t & 63, wv_ = t >> 6;
  const int m16 = lane & 15, quad = lane >> 4;
  const int rowbase = blockIdx.x * 128 + wv_ * 32;
  const bfu* brow0 = A + (size_t)(rowbase + m16) * 1024;
  const bfu* brow1 = A + (size_t)(rowbase + 16 + m16) * 1024;
  f32x4 acc[2][8];
#pragma unroll
  for (int rg = 0; rg < 2; rg++)
#pragma unroll
    for (int i = 0; i < 8; i++) acc[rg][i] = (f32x4){0.f, 0.f, 0.f, 0.f};
  for (int kk = 0; kk < 32; kk++) {
    int k0 = kk * 32 + quad * 8;
    f16x8 ahi0 = *(const f16x8*)(brow0 + k0);
    f16x8 ahi1 = *(const f16x8*)(brow1 + k0);
#pragma unroll
    for (int tt = 0; tt < 8; tt++) {
      int pos = ((((kk * 8 + tt) * 4 + quad) * 16) + m16) * 8;
      f16x8 bhi = *(const f16x8*)&Wtab[pos];
      acc[0][tt] = __builtin_amdgcn_mfma_f32_16x16x32_f16(ahi0, bhi, acc[0][tt], 0, 0, 0);
      acc[1][tt] = __builtin_amdgcn_mfma_f32_16x16x32_f16(ahi1, bhi, acc[1][tt], 0, 0, 0);
    }
  }
#pragma unroll
  for (int rg = 0; rg < 2; rg++) {
    const int rb = rowbase + rg * 16;
    float pl[4] = {0.f, 0.f, 0.f, 0.f}, pr[4] = {0.f, 0.f, 0.f, 0.f};
#pragma unroll
    for (int tt = 0; tt < 8; tt++) {
      int col = tt * 16 + m16;
      float alv = al[col], arv = ar[col];
#pragma unroll
      for (int r = 0; r < 4; r++) {
        float v = acc[rg][tt][r];
        out[(size_t)(rb + quad * 4 + r) * 128 + col] = v;
        pl[r] += v * alv;
        pr[r] += v * arv;
      }
    }
#pragma unroll
    for (int r = 0; r < 4; r++) {
      float a0 = pl[r], a1 = pr[r];
#pragma unroll
      for (int off = 1; off < 16; off <<= 1) {
        a0 += __shfl_xor(a0, off);
        a1 += __shfl_xor(a1, off);
      }
      if (m16 == 0) {
        el[rb + quad * 4 + r] = a0;
        er[rb + quad * 4 + r] = a1;
      }
    }
  }
}

// ---------------- attention logits (fallback path) ----------------
__global__ __launch_bounds__(64) void attn_logits_kernel(
    const float* __restrict__ f, const float* __restrict__ al,
    const float* __restrict__ ar, float* __restrict__ el,
    float* __restrict__ er) {
  int node = blockIdx.x, lane = threadIdx.x;
  float v1 = f[(size_t)node * 128 + lane];
  float v2 = f[(size_t)node * 128 + 64 + lane];
  float sl = v1 * al[lane] + v2 * al[64 + lane];
  float sr = v1 * ar[lane] + v2 * ar[64 + lane];
#pragma unroll
  for (int off = 32; off; off >>= 1) {
    sl += __shfl_down(sl, off);
    sr += __shfl_down(sr, off);
  }
  if (lane == 0) { el[node] = sl; er[node] = sr; }
}

// ---------------- CSR build ----------------
__global__ void hist_rank_kernel(const int* __restrict__ dst, int* __restrict__ cnt,
                                 int* __restrict__ rank, int nE) {
  int e = blockIdx.x * 256 + threadIdx.x;
  if (e < nE) rank[e] = atomicAdd(&cnt[dst[e]], 1);
}

__global__ __launch_bounds__(256) void scan_block_kernel(
    const int* __restrict__ cnt, int* __restrict__ excl, int* __restrict__ part) {
  __shared__ int s[256];
  int blk = blockIdx.x, tid = threadIdx.x;
  int base = blk * 1024 + tid * 4;
  int a0 = cnt[base], a1 = cnt[base + 1], a2 = cnt[base + 2], a3 = cnt[base + 3];
  int tsum = a0 + a1 + a2 + a3;
  s[tid] = tsum; __syncthreads();
  for (int off = 1; off < 256; off <<= 1) {
    int v = (tid >= off) ? s[tid - off] : 0;
    __syncthreads();
    s[tid] += v;
    __syncthreads();
  }
  int texcl = s[tid] - tsum;
  excl[base]     = texcl;
  excl[base + 1] = texcl + a0;
  excl[base + 2] = texcl + a0 + a1;
  excl[base + 3] = texcl + a0 + a1 + a2;
  if (tid == 255) part[blk] = s[255];
}

__global__ __launch_bounds__(128) void scan_part_kernel(int* __restrict__ part) {
  __shared__ int s[128];
  int tid = threadIdx.x;
  int orig = part[tid];
  s[tid] = orig; __syncthreads();
  for (int off = 1; off < 128; off <<= 1) {
    int v = (tid >= off) ? s[tid - off] : 0;
    __syncthreads();
    s[tid] += v;
    __syncthreads();
  }
  part[tid] = s[tid] - orig;
}

__global__ void scan_add_kernel(int* __restrict__ row_ptr, const int* __restrict__ part,
                                int n, int total) {
  int i = blockIdx.x * 256 + threadIdx.x;
  if (i < n) row_ptr[i] += part[i >> 10];
  if (i == 0) row_ptr[n] = total;
}

// single-block exclusive scan over 2048 counts (outer graph)
__global__ __launch_bounds__(256) void scan2048_kernel(const int* __restrict__ cnt,
                                                       int* __restrict__ rp, int total) {
  __shared__ int s[256];
  int t = threadIdx.x;
  int base = t * 8;
  int v[8];
  int tsum = 0;
#pragma unroll
  for (int i = 0; i < 8; i++) { v[i] = cnt[base + i]; tsum += v[i]; }
  s[t] = tsum; __syncthreads();
  for (int off = 1; off < 256; off <<= 1) {
    int x = (t >= off) ? s[t - off] : 0;
    __syncthreads();
    s[t] += x;
    __syncthreads();
  }
  int excl = s[t] - tsum;
#pragma unroll
  for (int i = 0; i < 8; i++) { rp[base + i] = excl; excl += v[i]; }
  if (t == 255) rp[2048] = total;
}

__global__ void scatter2_kernel(const int* __restrict__ dst, const int* __restrict__ src,
                                const int* __restrict__ row_ptr, const int* __restrict__ rank,
                                int* __restrict__ adj_src, int nE) {
  int e = blockIdx.x * 256 + threadIdx.x;
  if (e >= nE) return;
  adj_src[row_ptr[dst[e]] + rank[e]] = src[e];
}

// inner scatter with h packed into high bits: adj = src | (h[src] << 17)
__global__ void scatter2_pack_kernel(const int* __restrict__ dst, const int* __restrict__ src,
                                     const int* __restrict__ h,
                                     const int* __restrict__ row_ptr, const int* __restrict__ rank,
                                     int* __restrict__ adj_src, int nE) {
  int e = blockIdx.x * 256 + threadIdx.x;
  if (e >= nE) return;
  int s = src[e];
  adj_src[row_ptr[dst[e]] + rank[e]] = s | (h[s] << 17);
}

// ---------------- layer-1 fused aggregation: vocab-table gather (packed adj) ----------------
__global__ __launch_bounds__(256) void gat_aggregate_vocab_kernel(
    const bfu* __restrict__ fvh, const float* __restrict__ elv,
    const float* __restrict__ erv, const int* __restrict__ h,
    const int* __restrict__ row_ptr, const int* __restrict__ adj,
    const float* __restrict__ bias, bfu* __restrict__ outX) {
  const int t = threadIdx.x;
  const int l = t & 31;
  const int gb = t & 32;
  const int d = blockIdx.x * 8 + (t >> 5);
  const int c0 = l * 4;
  int beg = row_ptr[d];
  int n = row_ptr[d + 1] - beg;
  float4 bv = *(const float4*)&bias[c0];
  if (n == 0) {
    ushort4 o;
    o.x = f2h(fmaxf(bv.x, 0.f)); o.y = f2h(fmaxf(bv.y, 0.f));
    o.z = f2h(fmaxf(bv.z, 0.f)); o.w = f2h(fmaxf(bv.w, 0.f));
    *(ushort4*)&outX[(size_t)d * 128 + c0] = o;
    return;
  }
  float er_d = erv[h[d]];
  float4 acc = make_float4(0.f, 0.f, 0.f, 0.f);
  if (n <= 32) {
    int hv = 0; float sc = -INFINITY;
    if (l < n) {
      hv = adj[beg + l] >> 17;
      float v = elv[hv] + er_d;
      sc = v > 0.f ? v : 0.2f * v;
    }
    float m = sc;
#pragma unroll
    for (int off = 16; off; off >>= 1) m = fmaxf(m, __shfl_xor(m, off));
    float ex = (l < n) ? expf(sc - m) : 0.f;
    float s = ex;
#pragma unroll
    for (int off = 16; off; off >>= 1) s += __shfl_xor(s, off);
    float wt = ex / s;
    for (int j = 0; j < n; j += 4) {
      int   h0 = __shfl(hv, gb + j);
      float w0 = __shfl(wt, gb + j);
      int   j1 = (j + 1 < n) ? j + 1 : j;
      int   h1 = __shfl(hv, gb + j1); float w1 = (j + 1 < n) ? __shfl(wt, gb + j1) : 0.f;
      int   j2 = (j + 2 < n) ? j + 2 : j;
      int   h2 = __shfl(hv, gb + j2); float w2 = (j + 2 < n) ? __shfl(wt, gb + j2) : 0.f;
      int   j3 = (j + 3 < n) ? j + 3 : j;
      int   h3 = __shfl(hv, gb + j3); float w3 = (j + 3 < n) ? __shfl(wt, gb + j3) : 0.f;
      ushort4 f0 = *(const ushort4*)&fvh[(size_t)h0 * 128 + c0];
      ushort4 f1 = *(const ushort4*)&fvh[(size_t)h1 * 128 + c0];
      ushort4 f2 = *(const ushort4*)&fvh[(size_t)h2 * 128 + c0];
      ushort4 f3 = *(const ushort4*)&fvh[(size_t)h3 * 128 + c0];
      acc.x += w0 * h2f(f0.x) + w1 * h2f(f1.x) + w2 * h2f(f2.x) + w3 * h2f(f3.x);
      acc.y += w0 * h2f(f0.y) + w1 * h2f(f1.y) + w2 * h2f(f2.y) + w3 * h2f(f3.y);
      acc.z += w0 * h2f(f0.z) + w1 * h2f(f1.z) + w2 * h2f(f2.z) + w3 * h2f(f3.z);
      acc.w += w0 * h2f(f0.w) + w1 * h2f(f1.w) + w2 * h2f(f2.w) + w3 * h2f(f3.w);
    }
  } else {
    float lm = -INFINITY;
    for (int e = l; e < n; e += 32) {
      int hv = adj[beg + e] >> 17;
      float v = elv[hv] + er_d;
      v = v > 0.f ? v : 0.2f * v;
      lm = fmaxf(lm, v);
    }
#pragma unroll
    for (int off = 16; off; off >>= 1) lm = fmaxf(lm, __shfl_xor(lm, off));
    float ls = 0.f;
    for (int e = l; e < n; e += 32) {
      int hv = adj[beg + e] >> 17;
      float v = elv[hv] + er_d;
      v = v > 0.f ? v : 0.2f * v;
      ls += expf(v - lm);
    }
#pragma unroll
    for (int off = 16; off; off >>= 1) ls += __shfl_xor(ls, off);
    for (int base = 0; base < n; base += 32) {
      int e = base + l;
      int hv = 0; float wt = 0.f;
      if (e < n) {
        hv = adj[beg + e] >> 17;
        float v = elv[hv] + er_d;
        v = v > 0.f ? v : 0.2f * v;
        wt = expf(v - lm) / ls;
      }
      int cnt = min(32, n - base);
      for (int j = 0; j < cnt; ++j) {
        int h0 = __shfl(hv, gb + j);
        float w0 = __shfl(wt, gb + j);
        ushort4 f0 = *(const ushort4*)&fvh[(size_t)h0 * 128 + c0];
        acc.x += w0 * h2f(f0.x);
        acc.y += w0 * h2f(f0.y);
        acc.z += w0 * h2f(f0.z);
        acc.w += w0 * h2f(f0.w);
      }
    }
  }
  ushort4 o;
  o.x = f2h(fmaxf(acc.x + bv.x, 0.f));
  o.y = f2h(fmaxf(acc.y + bv.y, 0.f));
  o.z = f2h(fmaxf(acc.z + bv.z, 0.f));
  o.w = f2h(fmaxf(acc.w + bv.w, 0.f));
  *(ushort4*)&outX[(size_t)d * 128 + c0] = o;
}

// ---------------- fused CSR GAT aggregation (packed adj, fp16 F, fp16 out) ----------------
__global__ __launch_bounds__(256) void gat_aggregate_csr_kernel(
    const bfu* __restrict__ F, const float* __restrict__ el,
    const float* __restrict__ er, const int* __restrict__ row_ptr,
    const int* __restrict__ adj,
    const float* __restrict__ bias, bfu* __restrict__ outX) {
  const int t = threadIdx.x;
  const int l = t & 31;
  const int gb = t & 32;
  const int d = blockIdx.x * 8 + (t >> 5);
  const int c0 = l * 4;
  int beg = row_ptr[d];
  int n = row_ptr[d + 1] - beg;
  float4 bv = *(const float4*)&bias[c0];
  if (n == 0) {
    ushort4 o;
    o.x = f2h(fmaxf(bv.x, 0.f)); o.y = f2h(fmaxf(bv.y, 0.f));
    o.z = f2h(fmaxf(bv.z, 0.f)); o.w = f2h(fmaxf(bv.w, 0.f));
    *(ushort4*)&outX[(size_t)d * 128 + c0] = o;
    return;
  }
  float er_d = er[d];
  float4 acc = make_float4(0.f, 0.f, 0.f, 0.f);
  if (n <= 32) {
    int sv = 0; float sc = -INFINITY;
    if (l < n) {
      sv = adj[beg + l] & SRCMASK;
      float v = el[sv] + er_d;
      sc = v > 0.f ? v : 0.2f * v;
    }
    float m = sc;
#pragma unroll
    for (int off = 16; off; off >>= 1) m = fmaxf(m, __shfl_xor(m, off));
    float ex = (l < n) ? expf(sc - m) : 0.f;
    float s = ex;
#pragma unroll
    for (int off = 16; off; off >>= 1) s += __shfl_xor(s, off);
    float wt = ex / s;
    for (int j = 0; j < n; j += 4) {
      int   s0 = __shfl(sv, gb + j);
      float w0 = __shfl(wt, gb + j);
      int   j1 = (j + 1 < n) ? j + 1 : j;
      int   s1 = __shfl(sv, gb + j1); float w1 = (j + 1 < n) ? __shfl(wt, gb + j1) : 0.f;
      int   j2 = (j + 2 < n) ? j + 2 : j;
      int   s2 = __shfl(sv, gb + j2); float w2 = (j + 2 < n) ? __shfl(wt, gb + j2) : 0.f;
      int   j3 = (j + 3 < n) ? j + 3 : j;
      int   s3 = __shfl(sv, gb + j3); float w3 = (j + 3 < n) ? __shfl(wt, gb + j3) : 0.f;
      ushort4 f0 = *(const ushort4*)&F[(size_t)s0 * 128 + c0];
      ushort4 f1 = *(const ushort4*)&F[(size_t)s1 * 128 + c0];
      ushort4 f2 = *(const ushort4*)&F[(size_t)s2 * 128 + c0];
      ushort4 f3 = *(const ushort4*)&F[(size_t)s3 * 128 + c0];
      acc.x += w0 * h2f(f0.x) + w1 * h2f(f1.x) + w2 * h2f(f2.x) + w3 * h2f(f3.x);
      acc.y += w0 * h2f(f0.y) + w1 * h2f(f1.y) + w2 * h2f(f2.y) + w3 * h2f(f3.y);
      acc.z += w0 * h2f(f0.z) + w1 * h2f(f1.z) + w2 * h2f(f2.z) + w3 * h2f(f3.z);
      acc.w += w0 * h2f(f0.w) + w1 * h2f(f1.w) + w2 * h2f(f2.w) + w3 * h2f(f3.w);
    }
  } else {
    float lm = -INFINITY;
    for (int e = l; e < n; e += 32) {
      int sv = adj[beg + e] & SRCMASK;
      float v = el[sv] + er_d;
      v = v > 0.f ? v : 0.2f * v;
      lm = fmaxf(lm, v);
    }
#pragma unroll
    for (int off = 16; off; off >>= 1) lm = fmaxf(lm, __shfl_xor(lm, off));
    float ls = 0.f;
    for (int e = l; e < n; e += 32) {
      int sv = adj[beg + e] & SRCMASK;
      float v = el[sv] + er_d;
      v = v > 0.f ? v : 0.2f * v;
      ls += expf(v - lm);
    }
#pragma unroll
    for (int off = 16; off; off >>= 1) ls += __shfl_xor(ls, off);
    for (int base = 0; base < n; base += 32) {
      int e = base + l;
      int sv = 0; float wt = 0.f;
      if (e < n) {
        sv = adj[beg + e] & SRCMASK;
        float v = el[sv] + er_d;
        v = v > 0.f ? v : 0.2f * v;
        wt = expf(v - lm) / ls;
      }
      int cnt = min(32, n - base);
      for (int j = 0; j < cnt; ++j) {
        int s0 = __shfl(sv, gb + j);
        float w0 = __shfl(wt, gb + j);
        ushort4 f0 = *(const ushort4*)&F[(size_t)s0 * 128 + c0];
        acc.x += w0 * h2f(f0.x);
        acc.y += w0 * h2f(f0.y);
        acc.z += w0 * h2f(f0.z);
        acc.w += w0 * h2f(f0.w);
      }
    }
  }
  ushort4 o;
  o.x = f2h(fmaxf(acc.x + bv.x, 0.f));
  o.y = f2h(fmaxf(acc.y + bv.y, 0.f));
  o.z = f2h(fmaxf(acc.z + bv.z, 0.f));
  o.w = f2h(fmaxf(acc.w + bv.w, 0.f));
  *(ushort4*)&outX[(size_t)d * 128 + c0] = o;
}

// ---------------- fused outer GAT aggregation (fp32 f3 gather) ----------------
__global__ __launch_bounds__(256) void gat_aggregate_outer_kernel(
    const float* __restrict__ F, const float* __restrict__ el,
    const float* __restrict__ er, const int* __restrict__ row_ptr,
    const int* __restrict__ adj_src,
    const float* __restrict__ bias, float* __restrict__ outG) {
  const int t = threadIdx.x;
  const int l = t & 31;
  const int gb = t & 32;
  const int d = blockIdx.x * 8 + (t >> 5);
  const int c0 = l * 4;
  int beg = row_ptr[d];
  int n = row_ptr[d + 1] - beg;
  float4 bv = *(const float4*)&bias[c0];
  if (n == 0) {
    float4 o;
    o.x = fmaxf(bv.x, 0.f); o.y = fmaxf(bv.y, 0.f);
    o.z = fmaxf(bv.z, 0.f); o.w = fmaxf(bv.w, 0.f);
    *(float4*)&outG[(size_t)d * 128 + c0] = o;
    return;
  }
  float er_d = er[d];
  float4 acc = make_float4(0.f, 0.f, 0.f, 0.f);
  if (n <= 32) {
    int sv = 0; float sc = -INFINITY;
    if (l < n) {
      sv = adj_src[beg + l];
      float v = el[sv] + er_d;
      sc = v > 0.f ? v : 0.2f * v;
    }
    float m = sc;
#pragma unroll
    for (int off = 16; off; off >>= 1) m = fmaxf(m, __shfl_xor(m, off));
    float ex = (l < n) ? expf(sc - m) : 0.f;
    float s = ex;
#pragma unroll
    for (int off = 16; off; off >>= 1) s += __shfl_xor(s, off);
    float wt = ex / s;
    for (int j = 0; j < n; ++j) {
      int   s0 = __shfl(sv, gb + j);
      float w0 = __shfl(wt, gb + j);
      float4 f0 = *(const float4*)&F[(size_t)s0 * 128 + c0];
      acc.x += w0 * f0.x; acc.y += w0 * f0.y;
      acc.z += w0 * f0.z; acc.w += w0 * f0.w;
    }
  } else {
    float lm = -INFINITY;
    for (int e = l; e < n; e += 32) {
      int sv = adj_src[beg + e];
      float v = el[sv] + er_d;
      v = v > 0.f ? v : 0.2f * v;
      lm = fmaxf(lm, v);
    }
#pragma unroll
    for (int off = 16; off; off >>= 1) lm = fmaxf(lm, __shfl_xor(lm, off));
    float ls = 0.f;
    for (int e = l; e < n; e += 32) {
      int sv = adj_src[beg + e];
      float v = el[sv] + er_d;
      v = v > 0.f ? v : 0.2f * v;
      ls += expf(v - lm);
    }
#pragma unroll
    for (int off = 16; off; off >>= 1) ls += __shfl_xor(ls, off);
    for (int base = 0; base < n; base += 32) {
      int e = base + l;
      int sv = 0; float wt = 0.f;
      if (e < n) {
        sv = adj_src[beg + e];
        float v = el[sv] + er_d;
        v = v > 0.f ? v : 0.2f * v;
        wt = expf(v - lm) / ls;
      }
      int cnt = min(32, n - base);
      for (int j = 0; j < cnt; ++j) {
        int s0 = __shfl(sv, gb + j);
        float w0 = __shfl(wt, gb + j);
        float4 f0 = *(const float4*)&F[(size_t)s0 * 128 + c0];
        acc.x += w0 * f0.x; acc.y += w0 * f0.y;
        acc.z += w0 * f0.z; acc.w += w0 * f0.w;
      }
    }
  }
  float4 o;
  o.x = fmaxf(acc.x + bv.x, 0.f);
  o.y = fmaxf(acc.y + bv.y, 0.f);
  o.z = fmaxf(acc.z + bv.z, 0.f);
  o.w = fmaxf(acc.w + bv.w, 0.f);
  *(float4*)&outG[(size_t)d * 128 + c0] = o;
}

// ---------------- atomic-path edge kernels (fallback only) ----------------
static __device__ __forceinline__ void atomicMaxF(float* addr, float v) {
  int iv = __float_as_int(v);
  if (iv >= 0) atomicMax((int*)addr, iv);
  else atomicMin((unsigned int*)addr, (unsigned int)iv);
}

static __device__ __forceinline__ float edge_score(const float* el, const float* er,
                                                   int sv, int dv) {
  float v = el[sv] + er[dv];
  return v > 0.f ? v : 0.2f * v;
}

__global__ void edge_max_kernel(const float* __restrict__ el,
                                const float* __restrict__ er,
                                const int* __restrict__ src,
                                const int* __restrict__ dst,
                                float* __restrict__ m, int nE) {
  int e = blockIdx.x * 256 + threadIdx.x;
  if (e >= nE) return;
  atomicMaxF(&m[dst[e]], edge_score(el, er, src[e], dst[e]));
}

__global__ void edge_expsum_kernel(const float* __restrict__ el,
                                   const float* __restrict__ er,
                                   const float* __restrict__ m,
                                   const int* __restrict__ src,
                                   const int* __restrict__ dst,
                                   float* __restrict__ s, int nE) {
  int e = blockIdx.x * 256 + threadIdx.x;
  if (e >= nE) return;
  int d = dst[e];
  atomicAdd(&s[d], expf(edge_score(el, er, src[e], d) - m[d]));
}

__global__ __launch_bounds__(128) void edge_aggregate_kernel(
    const float* __restrict__ f, const float* __restrict__ el,
    const float* __restrict__ er, const float* __restrict__ m,
    const float* __restrict__ s, const int* __restrict__ src,
    const int* __restrict__ dst, float* __restrict__ out, int nE) {
  int e = blockIdx.x;
  int d = threadIdx.x;
  int sv = src[e], dv = dst[e];
  float alpha = expf(edge_score(el, er, sv, dv) - m[dv]) / s[dv];
  atomicAdd(&out[(size_t)dv * 128 + d], alpha * f[(size_t)sv * 128 + d]);
}

__global__ void bias_relu_kernel(float* __restrict__ x,
                                 const float* __restrict__ b, int total) {
  int i = blockIdx.x * 256 + threadIdx.x;
  if (i >= total) return;
  x[i] = fmaxf(x[i] + b[i & 127], 0.f);
}

// ---------------- sort pooling ----------------
__global__ __launch_bounds__(64) void row_max_kernel(const float* __restrict__ x,
                                                     float* __restrict__ key) {
  int node = blockIdx.x, lane = threadIdx.x;
  float v = fmaxf(x[(size_t)node * 128 + lane], x[(size_t)node * 128 + 64 + lane]);
#pragma unroll
  for (int off = 32; off; off >>= 1) v = fmaxf(v, __shfl_down(v, off));
  if (lane == 0) key[node] = v;
}

__global__ __launch_bounds__(64) void select_topk_kernel(
    const float* __restrict__ key, int* __restrict__ sel) {
  __shared__ float keys[NPG];
  int g = blockIdx.x, t = threadIdx.x;
  keys[t] = key[(size_t)g * NPG + t];
  __syncthreads();
  float myk = keys[t];
  int rank = 0;
  for (int j = 0; j < NPG; ++j) {
    float kj = keys[j];
    rank += (kj > myk) || (kj == myk && j < t);
  }
  if (rank < KK) sel[g * KK + rank] = t;
}

// fused top-k select + 8-row bitonic sort -> fp16 xp (CSR path)
__global__ __launch_bounds__(1024) void topk_sort_kernel(
    const float* __restrict__ keyb, const bfu* __restrict__ xin,
    bfu* __restrict__ xp) {
  __shared__ float keys[NPG];
  __shared__ int sel_l[KK];
  __shared__ float v[1024];
  int g = blockIdx.x, t = threadIdx.x;
  if (t < NPG) keys[t] = keyb[(size_t)g * NPG + t];
  __syncthreads();
  if (t < NPG) {
    float myk = keys[t];
    int rank = 0;
    for (int j = 0; j < NPG; ++j) {
      float kj = keys[j];
      rank += (kj > myk) || (kj == myk && j < t);
    }
    if (rank < KK) sel_l[rank] = t;
  }
  __syncthreads();
  int r = t >> 7, c = t & 127;
  int node = sel_l[r];
  v[t] = h2f(xin[(size_t)(g * NPG + node) * 128 + c]);
  __syncthreads();
  for (int k = 2; k <= 128; k <<= 1) {
    for (int j = k >> 1; j > 0; j >>= 1) {
      int ixj = c ^ j;
      if (ixj > c) {
        float a = v[r * 128 + c], bb = v[r * 128 + ixj];
        bool asc = ((c & k) == 0);
        if (asc ? (a > bb) : (a < bb)) { v[r * 128 + c] = bb; v[r * 128 + ixj] = a; }
      }
      __syncthreads();
    }
  }
  xp[(size_t)g * 1024 + t] = f2h(v[t]);
}

template <int HF>
__global__ __launch_bounds__(128) void sort_rows_kernel(
    const void* __restrict__ xin, const int* __restrict__ sel,
    float* __restrict__ xp) {
  __shared__ float v[128];
  int b = blockIdx.x;
  int t = threadIdx.x;
  int g = b >> 3, r = b & 7;
  int node = sel[b];
  if (HF) v[t] = h2f(((const bfu*)xin)[(size_t)(g * NPG + node) * 128 + t]);
  else    v[t] = ((const float*)xin)[(size_t)(g * NPG + node) * 128 + t];
  __syncthreads();
  for (int k = 2; k <= 128; k <<= 1) {
    for (int j = k >> 1; j > 0; j >>= 1) {
      int ixj = t ^ j;
      if (ixj > t) {
        float a = v[t], bb = v[ixj];
        bool asc = ((t & k) == 0);
        if (asc ? (a > bb) : (a < bb)) { v[t] = bb; v[ixj] = a; }
      }
      __syncthreads();
    }
  }
  xp[(size_t)g * (KK * 128) + r * 128 + t] = v[t];
}

// ---------------- fused tail MLP ----------------
__global__ __launch_bounds__(128) void mlp_tail_kernel(
    const float* __restrict__ g3, const float* __restrict__ Wl,
    const float* __restrict__ bl, const float* __restrict__ Wl1,
    const float* __restrict__ bl1, const float* __restrict__ Wc,
    const float* __restrict__ bc, float* __restrict__ out) {
  __shared__ float buf[128];
  __shared__ float r0[128], r1[128];
  int g = blockIdx.x, t = threadIdx.x;
  buf[t] = g3[(size_t)g * 128 + t];
  __syncthreads();
  float a = 0.f;
  for (int k = 0; k < 128; k++) a += buf[k] * Wl[k * 128 + t];
  float t1 = fmaxf(a + bl[t], 0.f);
  __syncthreads();
  buf[t] = t1;
  __syncthreads();
  a = 0.f;
  for (int k = 0; k < 128; k++) a += buf[k] * Wl1[k * 128 + t];
  float t2 = fmaxf(a + bl1[t], 0.f);
  r0[t] = t2 * Wc[t * 2 + 0];
  r1[t] = t2 * Wc[t * 2 + 1];
  __syncthreads();
  for (int off = 64; off; off >>= 1) {
    if (t < off) { r0[t] += r0[t + off]; r1[t] += r1[t + off]; }
    __syncthreads();
  }
  if (t == 0) {
    out[g * 2 + 0] = r0[0] + bc[0];
    out[g * 2 + 1] = r1[0] + bc[1];
  }
}

// ---------------- launcher ----------------
extern "C" void kernel_launch(void* const* d_in, const int* in_sizes, int n_in,
                              void* d_out, int out_size, void* d_ws, size_t ws_size,
                              hipStream_t stream) {
  const size_t BASE_FLOATS = (size_t)NN * DD * 2 + (size_t)NN * 4;  // X,F,el,er,mx,sm
  const size_t CSR_INTS = (size_t)(NN + 1) + NN + EE + 128;          // row_ptr,cursor,adj,part
  if (ws_size < BASE_FLOATS * sizeof(float)) {
    hipMemsetAsync(d_out, 0, (size_t)out_size * sizeof(float), stream);
    return;
  }
  const bool use_csr = ws_size >= BASE_FLOATS * sizeof(float) + CSR_INTS * sizeof(int);

  const int* h      = (const int*)d_in[0];
  const int* g_src  = (const int*)d_in[1];
  const int* g_dst  = (const int*)d_in[2];
  const int* fg_src = (const int*)d_in[3];
  const int* fg_dst = (const int*)d_in[4];
  const float* temb = (const float*)d_in[5];
  const float* W1 = (const float*)d_in[6];
  const float* al1 = (const float*)d_in[7];
  const float* ar1 = (const float*)d_in[8];
  const float* b1 = (const float*)d_in[9];
  const float* W2 = (const float*)d_in[10];
  const float* al2 = (const float*)d_in[11];
  const float* ar2 = (const float*)d_in[12];
  const float* b2 = (const float*)d_in[13];
  const float* W3 = (const float*)d_in[14];
  const float* al3 = (const float*)d_in[15];
  const float* ar3 = (const float*)d_in[16];
  const float* b3 = (const float*)d_in[17];
  const float* Wf = (const float*)d_in[18];
  const float* bfv = (const float*)d_in[19];
  const float* Wl = (const float*)d_in[20];
  const float* bl = (const float*)d_in[21];
  const float* Wl1 = (const float*)d_in[22];
  const float* bl1 = (const float*)d_in[23];
  const float* Wc = (const float*)d_in[24];
  const float* bc = (const float*)d_in[25];
  float* out = (float*)d_out;

  // ---- workspace layout ----
  float* ws = (float*)d_ws;
  float* X  = ws;                    // CSR: X fp16
  float* F  = X + (size_t)NN * DD;   // CSR: F fp16, later xp fp16 / f3 / keyb
  float* el = F + (size_t)NN * DD;
  float* er = el + NN;
  float* mx = er + NN;
  float* sm = mx + NN;
  int* row_ptr = (int*)(sm + NN);
  int* cursor  = row_ptr + NN + 1;
  int* adj_src = cursor + NN;
  int* part    = adj_src + EE;
  // rank buffer aliases X (X first written after CSR build):
  int* rankb = (int*)X;
  // packed W tables + vocab tables live in mx/sm scratch:
  bfu* w2h = (bfu*)mx;                      // 16384
  bfu* wfh = w2h + 16384;                   // 16384
  bfu* fvh = wfh + 16384;                   // VOCAB*128
  float* elv = (float*)(fvh + VOCAB * 128 + 128);
  float* erv = elv + VOCAB;
  bfu* w3h = (bfu*)(erv + VOCAB + 2);       // 131072 entries (256 KB)
  // outer-graph CSR aliases X start (X dead after topk_sort):
  int* ocnt  = (int*)X;               // 2048
  int* orp   = ocnt + 2048;           // 2049
  int* orank = orp + 2080;            // EFN
  int* oadj  = orank + EFN;           // EFN
  // carved from F once F is dead:
  float* xp   = F;                    // CSR: fp16 xp; fallback: fp32
  float* f3   = F + 2097152;
  float* g3   = f3 + (size_t)GG * DD;
  float* t1   = g3 + (size_t)GG * DD;
  float* t2   = t1 + (size_t)GG * DD;
  float* keyb = t2 + (size_t)GG * DD;
  int*   sel  = (int*)(keyb + NN);

  const int totalND = NN * DD;

  if (use_csr) {
    bfu* Fb  = (bfu*)F;
    bfu* Xb  = (bfu*)X;
    bfu* xph = (bfu*)xp;
    // ---- inner CSR (h packed into adj high bits) ----
    zero_int_kernel<<<NN / 256, 256, 0, stream>>>(cursor, NN);
    hist_rank_kernel<<<EE / 256, 256, 0, stream>>>(g_dst, cursor, rankb, EE);
    scan_block_kernel<<<NN / 1024, 256, 0, stream>>>(cursor, row_ptr, part);
    scan_part_kernel<<<1, 128, 0, stream>>>(part);
    scan_add_kernel<<<(NN + 255) / 256, 256, 0, stream>>>(row_ptr, part, NN, EE);
    scatter2_pack_kernel<<<EE / 256, 256, 0, stream>>>(g_dst, g_src, h, row_ptr, rankb, adj_src, EE);

    pack_w2_kernel<<<128, 256, 0, stream>>>(W2, Wf, w2h, wfh);
    pack_wk_kernel<<<512, 256, 0, stream>>>(W3, w3h, 131072);
    vocab_l1_kernel<<<VOCAB, 128, 0, stream>>>(temb, W1, al1, ar1, fvh, elv, erv);

    // layer 1: aggregate from L1-resident vocab table (packed h) -> X fp16
    gat_aggregate_vocab_kernel<<<NN / 8, 256, 0, stream>>>(
        fvh, elv, erv, h, row_ptr, adj_src, b1, Xb);

    // layer 2: fp16 A MFMA -> F fp16 + logits; aggregate -> X fp16
    mfma_gemm<1><<<NN / 128, 256, 0, stream>>>(
        Xb, w2h, nullptr, Fb, al2, ar2, el, er, nullptr);
    gat_aggregate_csr_kernel<<<NN / 8, 256, 0, stream>>>(Fb, el, er, row_ptr, adj_src, b2, Xb);

    // linear_forward in-place (fp16) + fused fp32 row-max key
    mfma_gemm<2><<<NN / 128, 256, 0, stream>>>(
        Xb, wfh, bfv, Xb, nullptr, nullptr, nullptr, nullptr, keyb);

    // fused sort pooling -> xp (fp16)
    topk_sort_kernel<<<GG, 1024, 0, stream>>>(keyb, Xb, xph);

    // outer CSR build (multi-block; X start dead now)
    zero_int_kernel<<<GG / 256, 256, 0, stream>>>(ocnt, GG);
    hist_rank_kernel<<<EFN / 256, 256, 0, stream>>>(fg_dst, ocnt, orank, EFN);
    scan2048_kernel<<<1, 256, 0, stream>>>(ocnt, orp, EFN);
    scatter2_kernel<<<EFN / 256, 256, 0, stream>>>(fg_dst, fg_src, orp, orank, oadj, EFN);

    // outer GAT: MFMA GEMM (+fused logits) + fused aggregate
    mfma_gemm1024_kernel<<<GG / 128, 256, 0, stream>>>(xph, w3h, f3, al3, ar3, el, er);
    gat_aggregate_outer_kernel<<<GG / 8, 256, 0, stream>>>(f3, el, er, orp, oadj, b3, g3);

    // fused tail
    mlp_tail_kernel<<<GG, 128, 0, stream>>>(g3, Wl, bl, Wl1, bl1, Wc, bc, out);
  } else {
    embed_relu_kernel<<<totalND / 256, 256, 0, stream>>>(temb, h, X, totalND);
    auto gat_inner = [&](const float* W, const float* al, const float* ar, const float* bb) {
      gemm_kernel<DD, 8><<<NN / 8, 128, 0, stream>>>(X, W, nullptr, F, 0);
      attn_logits_kernel<<<NN, 64, 0, stream>>>(F, al, ar, el, er);
      init_softmax_kernel<<<(NN + 255) / 256, 256, 0, stream>>>(mx, sm, NN);
      fill_f32_kernel<<<totalND / 256, 256, 0, stream>>>(X, 0.f, totalND);
      edge_max_kernel<<<(EE + 255) / 256, 256, 0, stream>>>(el, er, g_src, g_dst, mx, EE);
      edge_expsum_kernel<<<(EE + 255) / 256, 256, 0, stream>>>(el, er, mx, g_src, g_dst, sm, EE);
      edge_aggregate_kernel<<<EE, 128, 0, stream>>>(F, el, er, mx, sm, g_src, g_dst, X, EE);
      bias_relu_kernel<<<totalND / 256, 256, 0, stream>>>(X, bb, totalND);
    };
    gat_inner(W1, al1, ar1, b1);
    gat_inner(W2, al2, ar2, b2);
    gemm_kernel<DD, 8><<<NN / 8, 128, 0, stream>>>(X, Wf, bfv, X, 1);
    row_max_kernel<<<NN, 64, 0, stream>>>(X, keyb);

    select_topk_kernel<<<GG, 64, 0, stream>>>(keyb, sel);
    sort_rows_kernel<0><<<GG * KK, 128, 0, stream>>>(X, sel, xp);

    gemm1024_kernel<<<GG / 8, 256, 0, stream>>>(xp, W3, f3, al3, ar3, el, er);
    init_softmax_kernel<<<(GG + 255) / 256, 256, 0, stream>>>(mx, sm, GG);
    fill_f32_kernel<<<(GG * DD + 255) / 256, 256, 0, stream>>>(g3, 0.f, GG * DD);
    edge_max_kernel<<<(EFN + 255) / 256, 256, 0, stream>>>(el, er, fg_src, fg_dst, mx, EFN);
    edge_expsum_kernel<<<(EFN + 255) / 256, 256, 0, stream>>>(el, er, mx, fg_src, fg_dst, sm, EFN);
    edge_aggregate_kernel<<<EFN, 128, 0, stream>>>(f3, el, er, mx, sm, fg_src, fg_dst, g3, EFN);
    bias_relu_kernel<<<(GG * DD + 255) / 256, 256, 0, stream>>>(g3, b3, GG * DD);
    mlp_tail_kernel<<<GG, 128, 0, stream>>>(g3, Wl, bl, Wl1, bl1, Wc, bc, out);
  }
}

// Round 10
// 433.736 us; speedup vs baseline: 1.1352x; 1.0106x over previous
//
#include <hip/hip_runtime.h>
#include <math.h>

#define NN   131072   // total inner nodes
#define GG   2048     // graphs
#define NPG  64       // nodes per graph
#define EE   1048576  // inner edges
#define EFN  32768    // outer edges
#define DD   128      // feature dim
#define KK   8        // sortpool k
#define VOCAB 150

typedef unsigned short bfu;  // raw 16-bit float bits (fp16 on CSR path)
typedef _Float16 f16x8 __attribute__((ext_vector_type(8)));
typedef float f32x4 __attribute__((ext_vector_type(4)));

static __device__ __forceinline__ bfu f2h(float f) {  // RNE f32 -> fp16 bits
  _Float16 h = (_Float16)f;
  bfu u;
  __builtin_memcpy(&u, &h, 2);
  return u;
}
static __device__ __forceinline__ float h2f(bfu b) {
  _Float16 h;
  __builtin_memcpy(&h, &b, 2);
  return (float)h;
}

// ---------------- utility ----------------
__global__ void fill_f32_kernel(float* __restrict__ p, float v, int nElems) {
  int i = blockIdx.x * 256 + threadIdx.x;
  if (i < nElems) p[i] = v;
}

__global__ void zero_int_kernel(int* __restrict__ p, int nElems) {
  int i = blockIdx.x * 256 + threadIdx.x;
  if (i < nElems) p[i] = 0;
}

__global__ void init_softmax_kernel(float* __restrict__ mx, float* __restrict__ sm, int nElems) {
  int i = blockIdx.x * 256 + threadIdx.x;
  if (i < nElems) { mx[i] = -INFINITY; sm[i] = 0.f; }
}

// x[i] = relu(token_emb[h[node]][d])   (fallback path only)
__global__ void embed_relu_kernel(const float* __restrict__ temb,
                                  const int* __restrict__ h,
                                  float* __restrict__ x, int total) {
  int i = blockIdx.x * 256 + threadIdx.x;
  if (i >= total) return;
  int node = i >> 7, d = i & 127;
  x[i] = fmaxf(temb[h[node] * DD + d], 0.f);
}

// ---------------- small / generic GEMM (fallback) ----------------
template <int KD, int ROWS>
__global__ __launch_bounds__(128) void gemm_kernel(
    const float* __restrict__ A, const float* __restrict__ W,
    const float* __restrict__ bias, float* __restrict__ out,
    int relu_flag) {
  __shared__ float As[ROWS * KD];
  const int row0 = blockIdx.x * ROWS;
  const int tid = threadIdx.x;
  for (int i = tid; i < ROWS * KD; i += 128) As[i] = A[(size_t)row0 * KD + i];
  __syncthreads();
  float acc[ROWS];
#pragma unroll
  for (int r = 0; r < ROWS; r++) acc[r] = 0.f;
  for (int k = 0; k < KD; k++) {
    float w = W[k * 128 + tid];
#pragma unroll
    for (int r = 0; r < ROWS; r++) acc[r] += As[r * KD + k] * w;
  }
  float b = bias ? bias[tid] : 0.f;
#pragma unroll
  for (int r = 0; r < ROWS; r++) {
    float v = acc[r] + b;
    if (relu_flag) v = fmaxf(v, 0.f);
    out[(size_t)(row0 + r) * 128 + tid] = v;
  }
}

// ---------------- vocab layer-1 table: fv = relu(temb) @ W1, logits ----------------
__global__ __launch_bounds__(128) void vocab_l1_kernel(
    const float* __restrict__ temb, const float* __restrict__ W1,
    const float* __restrict__ al1, const float* __restrict__ ar1,
    bfu* __restrict__ fvh, float* __restrict__ elv, float* __restrict__ erv) {
  __shared__ float xs[128];
  __shared__ float rl[128], rr[128];
  int v = blockIdx.x, t = threadIdx.x;
  xs[t] = fmaxf(temb[v * 128 + t], 0.f);
  __syncthreads();
  float acc = 0.f;
  for (int k = 0; k < 128; k++) acc += xs[k] * W1[k * 128 + t];
  fvh[v * 128 + t] = f2h(acc);
  rl[t] = acc * al1[t];
  rr[t] = acc * ar1[t];
  __syncthreads();
  for (int off = 64; off; off >>= 1) {
    if (t < off) { rl[t] += rl[t + off]; rr[t] += rr[t + off]; }
    __syncthreads();
  }
  if (t == 0) { elv[v] = rl[0]; erv[v] = rr[0]; }
}

// ---------------- outer-GAT GEMM + fused attention logits ----------------
__global__ __launch_bounds__(256) void gemm1024_kernel(
    const float* __restrict__ A, const float* __restrict__ W,
    float* __restrict__ out,
    const float* __restrict__ al, const float* __restrict__ ar,
    float* __restrict__ el, float* __restrict__ er) {
  __shared__ float As[8 * 1024];
  __shared__ float red[8][256];
  const int t = threadIdx.x;
  const int row0 = blockIdx.x * 8;
  for (int idx = t; idx < 8 * 256; idx += 256) {
    int r = idx >> 8, c4 = (idx & 255) << 2;
    *(float4*)&As[r * 1024 + c4] = *(const float4*)(A + (size_t)(row0 + r) * 1024 + c4);
  }
  __syncthreads();
  const int col = t & 127, kh = t >> 7;
  const int k0 = kh * 512;
  float acc[8];
#pragma unroll
  for (int r = 0; r < 8; r++) acc[r] = 0.f;
  for (int k = k0; k < k0 + 512; k += 4) {
    float w0 = W[(size_t)(k + 0) * 128 + col];
    float w1 = W[(size_t)(k + 1) * 128 + col];
    float w2 = W[(size_t)(k + 2) * 128 + col];
    float w3 = W[(size_t)(k + 3) * 128 + col];
#pragma unroll
    for (int r = 0; r < 8; r++) {
      float4 a = *(const float4*)&As[r * 1024 + k];
      acc[r] += a.x * w0 + a.y * w1 + a.z * w2 + a.w * w3;
    }
  }
#pragma unroll
  for (int r = 0; r < 8; r++) red[r][t] = acc[r];
  __syncthreads();
  // write out + stage logit products into As (A-staging is dead now)
  for (int idx = t; idx < 1024; idx += 256) {
    int r = idx >> 7, c = idx & 127;
    float val = red[r][c] + red[r][128 + c];
    out[(size_t)(row0 + r) * 128 + c] = val;
    As[idx] = val * al[c];
    As[4096 + idx] = val * ar[c];
  }
  __syncthreads();
  if (t < 8) {
    float s = 0.f;
    for (int c = 0; c < 128; c++) s += As[t * 128 + c];
    el[row0 + t] = s;
  } else if (t < 16) {
    int r = t - 8;
    float s = 0.f;
    for (int c = 0; c < 128; c++) s += As[4096 + r * 128 + c];
    er[row0 + r] = s;
  }
}

// ---------------- W pack: fragment-ordered fp16 tables (W2 + Wf in one launch) ----------------
__global__ void pack_w2_kernel(const float* __restrict__ W2, const float* __restrict__ Wf,
                               bfu* __restrict__ w2h, bfu* __restrict__ wfh) {
  int i = blockIdx.x * 256 + threadIdx.x;  // 0..32767
  if (i >= 32768) return;
  const float* W = (i < 16384) ? W2 : Wf;
  bfu* dst = (i < 16384) ? w2h : wfh;
  int ii = i & 16383;
  int k = ii >> 7, n = ii & 127;
  bfu h = f2h(W[ii]);
  int kk = k >> 5, k5 = k & 31, quad = k5 >> 3, j = k5 & 7;
  int tt = n >> 4, m16 = n & 15;
  int pos = ((((kk * 8 + tt) * 4 + quad) * 16) + m16) * 8 + j;
  dst[pos] = h;
}

// ---------------- MFMA GEMM (LDS-free, 32 rows/wave), fp16 A, hi-only W ----------------
// EPI: 1 = fp16 F out + attention logits,  2 = fp16 out in-place + fp32 row-max key
template <int EPI>
__global__ __launch_bounds__(256) void mfma_gemm(
    const bfu* __restrict__ A, const bfu* __restrict__ WfHi,
    const float* __restrict__ bias, bfu* __restrict__ outF,
    const float* __restrict__ al, const float* __restrict__ ar,
    float* __restrict__ el, float* __restrict__ er,
    float* __restrict__ keyb) {
  const int t = threadIdx.x;
  const int lane = t & 63, wv_ = t >> 6;
  const int m16 = lane & 15, quad = lane >> 4;
  const int rowbase = blockIdx.x * 128 + wv_ * 32;
  const bfu* brow0 = A + (size_t)(rowbase + m16) * 128;
  const bfu* brow1 = A + (size_t)(rowbase + 16 + m16) * 128;
  f32x4 acc[2][8];
#pragma unroll
  for (int rg = 0; rg < 2; rg++)
#pragma unroll
    for (int i = 0; i < 8; i++) acc[rg][i] = (f32x4){0.f, 0.f, 0.f, 0.f};
#pragma unroll
  for (int kk = 0; kk < 4; kk++) {
    int k0 = kk * 32 + quad * 8;
    f16x8 ahi0 = *(const f16x8*)(brow0 + k0);
    f16x8 ahi1 = *(const f16x8*)(brow1 + k0);
#pragma unroll
    for (int tt = 0; tt < 8; tt++) {
      int pos = ((((kk * 8 + tt) * 4 + quad) * 16) + m16) * 8;
      f16x8 bhi = *(const f16x8*)&WfHi[pos];
      acc[0][tt] = __builtin_amdgcn_mfma_f32_16x16x32_f16(ahi0, bhi, acc[0][tt], 0, 0, 0);
      acc[1][tt] = __builtin_amdgcn_mfma_f32_16x16x32_f16(ahi1, bhi, acc[1][tt], 0, 0, 0);
    }
  }
#pragma unroll
  for (int rg = 0; rg < 2; rg++) {
    const int rb = rowbase + rg * 16;
    if constexpr (EPI == 1) {
      float pl[4] = {0.f, 0.f, 0.f, 0.f}, pr[4] = {0.f, 0.f, 0.f, 0.f};
#pragma unroll
      for (int tt = 0; tt < 8; tt++) {
        int col = tt * 16 + m16;
        float alv = al[col], arv = ar[col];
#pragma unroll
        for (int r = 0; r < 4; r++) {
          float v = acc[rg][tt][r];
          outF[(size_t)(rb + quad * 4 + r) * 128 + col] = f2h(v);
          pl[r] += v * alv;
          pr[r] += v * arv;
        }
      }
#pragma unroll
      for (int r = 0; r < 4; r++) {
        float a0 = pl[r], a1 = pr[r];
#pragma unroll
        for (int off = 1; off < 16; off <<= 1) {
          a0 += __shfl_xor(a0, off);
          a1 += __shfl_xor(a1, off);
        }
        if (m16 == 0) {
          el[rb + quad * 4 + r] = a0;
          er[rb + quad * 4 + r] = a1;
        }
      }
    } else {
      float pm[4] = {-INFINITY, -INFINITY, -INFINITY, -INFINITY};
#pragma unroll
      for (int tt = 0; tt < 8; tt++) {
        int col = tt * 16 + m16;
        float bv = bias[col];
#pragma unroll
        for (int r = 0; r < 4; r++) {
          float v = fmaxf(acc[rg][tt][r] + bv, 0.f);
          outF[(size_t)(rb + quad * 4 + r) * 128 + col] = f2h(v);
          pm[r] = fmaxf(pm[r], v);
        }
      }
#pragma unroll
      for (int r = 0; r < 4; r++) {
        float a0 = pm[r];
#pragma unroll
        for (int off = 1; off < 16; off <<= 1) a0 = fmaxf(a0, __shfl_xor(a0, off));
        if (m16 == 0) keyb[rb + quad * 4 + r] = a0;
      }
    }
  }
}

// ---------------- attention logits (fallback path) ----------------
__global__ __launch_bounds__(64) void attn_logits_kernel(
    const float* __restrict__ f, const float* __restrict__ al,
    const float* __restrict__ ar, float* __restrict__ el,
    float* __restrict__ er) {
  int node = blockIdx.x, lane = threadIdx.x;
  float v1 = f[(size_t)node * 128 + lane];
  float v2 = f[(size_t)node * 128 + 64 + lane];
  float sl = v1 * al[lane] + v2 * al[64 + lane];
  float sr = v1 * ar[lane] + v2 * ar[64 + lane];
#pragma unroll
  for (int off = 32; off; off >>= 1) {
    sl += __shfl_down(sl, off);
    sr += __shfl_down(sr, off);
  }
  if (lane == 0) { el[node] = sl; er[node] = sr; }
}

// ---------------- CSR build ----------------
__global__ void hist_rank_kernel(const int* __restrict__ dst, int* __restrict__ cnt,
                                 int* __restrict__ rank, int nE) {
  int e = blockIdx.x * 256 + threadIdx.x;
  if (e < nE) rank[e] = atomicAdd(&cnt[dst[e]], 1);
}

__global__ __launch_bounds__(256) void scan_block_kernel(
    const int* __restrict__ cnt, int* __restrict__ excl, int* __restrict__ part) {
  __shared__ int s[256];
  int blk = blockIdx.x, tid = threadIdx.x;
  int base = blk * 1024 + tid * 4;
  int a0 = cnt[base], a1 = cnt[base + 1], a2 = cnt[base + 2], a3 = cnt[base + 3];
  int tsum = a0 + a1 + a2 + a3;
  s[tid] = tsum; __syncthreads();
  for (int off = 1; off < 256; off <<= 1) {
    int v = (tid >= off) ? s[tid - off] : 0;
    __syncthreads();
    s[tid] += v;
    __syncthreads();
  }
  int texcl = s[tid] - tsum;
  excl[base]     = texcl;
  excl[base + 1] = texcl + a0;
  excl[base + 2] = texcl + a0 + a1;
  excl[base + 3] = texcl + a0 + a1 + a2;
  if (tid == 255) part[blk] = s[255];
}

__global__ __launch_bounds__(128) void scan_part_kernel(int* __restrict__ part) {
  __shared__ int s[128];
  int tid = threadIdx.x;
  int orig = part[tid];
  s[tid] = orig; __syncthreads();
  for (int off = 1; off < 128; off <<= 1) {
    int v = (tid >= off) ? s[tid - off] : 0;
    __syncthreads();
    s[tid] += v;
    __syncthreads();
  }
  part[tid] = s[tid] - orig;
}

__global__ void scan_add_kernel(int* __restrict__ row_ptr, const int* __restrict__ part,
                                int n, int total) {
  int i = blockIdx.x * 256 + threadIdx.x;
  if (i < n) row_ptr[i] += part[i >> 10];
  if (i == 0) row_ptr[n] = total;
}

// single-block exclusive scan over 2048 counts (outer graph)
__global__ __launch_bounds__(256) void scan2048_kernel(const int* __restrict__ cnt,
                                                       int* __restrict__ rp, int total) {
  __shared__ int s[256];
  int t = threadIdx.x;
  int base = t * 8;
  int v[8];
  int tsum = 0;
#pragma unroll
  for (int i = 0; i < 8; i++) { v[i] = cnt[base + i]; tsum += v[i]; }
  s[t] = tsum; __syncthreads();
  for (int off = 1; off < 256; off <<= 1) {
    int x = (t >= off) ? s[t - off] : 0;
    __syncthreads();
    s[t] += x;
    __syncthreads();
  }
  int excl = s[t] - tsum;
#pragma unroll
  for (int i = 0; i < 8; i++) { rp[base + i] = excl; excl += v[i]; }
  if (t == 255) rp[2048] = total;
}

__global__ void scatter2_kernel(const int* __restrict__ dst, const int* __restrict__ src,
                                const int* __restrict__ row_ptr, const int* __restrict__ rank,
                                int* __restrict__ adj_src, int nE) {
  int e = blockIdx.x * 256 + threadIdx.x;
  if (e >= nE) return;
  adj_src[row_ptr[dst[e]] + rank[e]] = src[e];
}

// inner scatter writing dual adjacency: plain src ints + uint8 vocab ids
__global__ void scatter2_dual_kernel(const int* __restrict__ dst, const int* __restrict__ src,
                                     const int* __restrict__ h,
                                     const int* __restrict__ row_ptr, const int* __restrict__ rank,
                                     int* __restrict__ adj_src,
                                     unsigned char* __restrict__ adjh, int nE) {
  int e = blockIdx.x * 256 + threadIdx.x;
  if (e >= nE) return;
  int s = src[e];
  int pos = row_ptr[dst[e]] + rank[e];
  adj_src[pos] = s;
  adjh[pos] = (unsigned char)h[s];
}

// ---------------- layer-1 fused aggregation: vocab-table gather (uint8 adjh) ----------------
__global__ __launch_bounds__(256) void gat_aggregate_vocab_kernel(
    const bfu* __restrict__ fvh, const float* __restrict__ elv,
    const float* __restrict__ erv, const int* __restrict__ h,
    const int* __restrict__ row_ptr, const unsigned char* __restrict__ adjh,
    const float* __restrict__ bias, bfu* __restrict__ outX) {
  const int t = threadIdx.x;
  const int l = t & 31;
  const int gb = t & 32;
  const int d = blockIdx.x * 8 + (t >> 5);
  const int c0 = l * 4;
  int beg = row_ptr[d];
  int n = row_ptr[d + 1] - beg;
  float4 bv = *(const float4*)&bias[c0];
  if (n == 0) {
    ushort4 o;
    o.x = f2h(fmaxf(bv.x, 0.f)); o.y = f2h(fmaxf(bv.y, 0.f));
    o.z = f2h(fmaxf(bv.z, 0.f)); o.w = f2h(fmaxf(bv.w, 0.f));
    *(ushort4*)&outX[(size_t)d * 128 + c0] = o;
    return;
  }
  float er_d = erv[h[d]];
  float4 acc = make_float4(0.f, 0.f, 0.f, 0.f);
  if (n <= 32) {
    int hv = 0; float sc = -INFINITY;
    if (l < n) {
      hv = adjh[beg + l];
      float v = elv[hv] + er_d;
      sc = v > 0.f ? v : 0.2f * v;
    }
    float m = sc;
#pragma unroll
    for (int off = 16; off; off >>= 1) m = fmaxf(m, __shfl_xor(m, off));
    float ex = (l < n) ? expf(sc - m) : 0.f;
    float s = ex;
#pragma unroll
    for (int off = 16; off; off >>= 1) s += __shfl_xor(s, off);
    float wt = ex / s;
    for (int j = 0; j < n; j += 4) {
      int   h0 = __shfl(hv, gb + j);
      float w0 = __shfl(wt, gb + j);
      int   j1 = (j + 1 < n) ? j + 1 : j;
      int   h1 = __shfl(hv, gb + j1); float w1 = (j + 1 < n) ? __shfl(wt, gb + j1) : 0.f;
      int   j2 = (j + 2 < n) ? j + 2 : j;
      int   h2 = __shfl(hv, gb + j2); float w2 = (j + 2 < n) ? __shfl(wt, gb + j2) : 0.f;
      int   j3 = (j + 3 < n) ? j + 3 : j;
      int   h3 = __shfl(hv, gb + j3); float w3 = (j + 3 < n) ? __shfl(wt, gb + j3) : 0.f;
      ushort4 f0 = *(const ushort4*)&fvh[(size_t)h0 * 128 + c0];
      ushort4 f1 = *(const ushort4*)&fvh[(size_t)h1 * 128 + c0];
      ushort4 f2 = *(const ushort4*)&fvh[(size_t)h2 * 128 + c0];
      ushort4 f3 = *(const ushort4*)&fvh[(size_t)h3 * 128 + c0];
      acc.x += w0 * h2f(f0.x) + w1 * h2f(f1.x) + w2 * h2f(f2.x) + w3 * h2f(f3.x);
      acc.y += w0 * h2f(f0.y) + w1 * h2f(f1.y) + w2 * h2f(f2.y) + w3 * h2f(f3.y);
      acc.z += w0 * h2f(f0.z) + w1 * h2f(f1.z) + w2 * h2f(f2.z) + w3 * h2f(f3.z);
      acc.w += w0 * h2f(f0.w) + w1 * h2f(f1.w) + w2 * h2f(f2.w) + w3 * h2f(f3.w);
    }
  } else {
    float lm = -INFINITY;
    for (int e = l; e < n; e += 32) {
      int hv = adjh[beg + e];
      float v = elv[hv] + er_d;
      v = v > 0.f ? v : 0.2f * v;
      lm = fmaxf(lm, v);
    }
#pragma unroll
    for (int off = 16; off; off >>= 1) lm = fmaxf(lm, __shfl_xor(lm, off));
    float ls = 0.f;
    for (int e = l; e < n; e += 32) {
      int hv = adjh[beg + e];
      float v = elv[hv] + er_d;
      v = v > 0.f ? v : 0.2f * v;
      ls += expf(v - lm);
    }
#pragma unroll
    for (int off = 16; off; off >>= 1) ls += __shfl_xor(ls, off);
    for (int base = 0; base < n; base += 32) {
      int e = base + l;
      int hv = 0; float wt = 0.f;
      if (e < n) {
        hv = adjh[beg + e];
        float v = elv[hv] + er_d;
        v = v > 0.f ? v : 0.2f * v;
        wt = expf(v - lm) / ls;
      }
      int cnt = min(32, n - base);
      for (int j = 0; j < cnt; ++j) {
        int h0 = __shfl(hv, gb + j);
        float w0 = __shfl(wt, gb + j);
        ushort4 f0 = *(const ushort4*)&fvh[(size_t)h0 * 128 + c0];
        acc.x += w0 * h2f(f0.x);
        acc.y += w0 * h2f(f0.y);
        acc.z += w0 * h2f(f0.z);
        acc.w += w0 * h2f(f0.w);
      }
    }
  }
  ushort4 o;
  o.x = f2h(fmaxf(acc.x + bv.x, 0.f));
  o.y = f2h(fmaxf(acc.y + bv.y, 0.f));
  o.z = f2h(fmaxf(acc.z + bv.z, 0.f));
  o.w = f2h(fmaxf(acc.w + bv.w, 0.f));
  *(ushort4*)&outX[(size_t)d * 128 + c0] = o;
}

// ---------------- fused CSR GAT aggregation (plain adj, fp16 F, fp16 out) ----------------
__global__ __launch_bounds__(256) void gat_aggregate_csr_kernel(
    const bfu* __restrict__ F, const float* __restrict__ el,
    const float* __restrict__ er, const int* __restrict__ row_ptr,
    const int* __restrict__ adj_src,
    const float* __restrict__ bias, bfu* __restrict__ outX) {
  const int t = threadIdx.x;
  const int l = t & 31;
  const int gb = t & 32;
  const int d = blockIdx.x * 8 + (t >> 5);
  const int c0 = l * 4;
  int beg = row_ptr[d];
  int n = row_ptr[d + 1] - beg;
  float4 bv = *(const float4*)&bias[c0];
  if (n == 0) {
    ushort4 o;
    o.x = f2h(fmaxf(bv.x, 0.f)); o.y = f2h(fmaxf(bv.y, 0.f));
    o.z = f2h(fmaxf(bv.z, 0.f)); o.w = f2h(fmaxf(bv.w, 0.f));
    *(ushort4*)&outX[(size_t)d * 128 + c0] = o;
    return;
  }
  float er_d = er[d];
  float4 acc = make_float4(0.f, 0.f, 0.f, 0.f);
  if (n <= 32) {
    int sv = 0; float sc = -INFINITY;
    if (l < n) {
      sv = adj_src[beg + l];
      float v = el[sv] + er_d;
      sc = v > 0.f ? v : 0.2f * v;
    }
    float m = sc;
#pragma unroll
    for (int off = 16; off; off >>= 1) m = fmaxf(m, __shfl_xor(m, off));
    float ex = (l < n) ? expf(sc - m) : 0.f;
    float s = ex;
#pragma unroll
    for (int off = 16; off; off >>= 1) s += __shfl_xor(s, off);
    float wt = ex / s;
    for (int j = 0; j < n; j += 4) {
      int   s0 = __shfl(sv, gb + j);
      float w0 = __shfl(wt, gb + j);
      int   j1 = (j + 1 < n) ? j + 1 : j;
      int   s1 = __shfl(sv, gb + j1); float w1 = (j + 1 < n) ? __shfl(wt, gb + j1) : 0.f;
      int   j2 = (j + 2 < n) ? j + 2 : j;
      int   s2 = __shfl(sv, gb + j2); float w2 = (j + 2 < n) ? __shfl(wt, gb + j2) : 0.f;
      int   j3 = (j + 3 < n) ? j + 3 : j;
      int   s3 = __shfl(sv, gb + j3); float w3 = (j + 3 < n) ? __shfl(wt, gb + j3) : 0.f;
      ushort4 f0 = *(const ushort4*)&F[(size_t)s0 * 128 + c0];
      ushort4 f1 = *(const ushort4*)&F[(size_t)s1 * 128 + c0];
      ushort4 f2 = *(const ushort4*)&F[(size_t)s2 * 128 + c0];
      ushort4 f3 = *(const ushort4*)&F[(size_t)s3 * 128 + c0];
      acc.x += w0 * h2f(f0.x) + w1 * h2f(f1.x) + w2 * h2f(f2.x) + w3 * h2f(f3.x);
      acc.y += w0 * h2f(f0.y) + w1 * h2f(f1.y) + w2 * h2f(f2.y) + w3 * h2f(f3.y);
      acc.z += w0 * h2f(f0.z) + w1 * h2f(f1.z) + w2 * h2f(f2.z) + w3 * h2f(f3.z);
      acc.w += w0 * h2f(f0.w) + w1 * h2f(f1.w) + w2 * h2f(f2.w) + w3 * h2f(f3.w);
    }
  } else {
    float lm = -INFINITY;
    for (int e = l; e < n; e += 32) {
      int sv = adj_src[beg + e];
      float v = el[sv] + er_d;
      v = v > 0.f ? v : 0.2f * v;
      lm = fmaxf(lm, v);
    }
#pragma unroll
    for (int off = 16; off; off >>= 1) lm = fmaxf(lm, __shfl_xor(lm, off));
    float ls = 0.f;
    for (int e = l; e < n; e += 32) {
      int sv = adj_src[beg + e];
      float v = el[sv] + er_d;
      v = v > 0.f ? v : 0.2f * v;
      ls += expf(v - lm);
    }
#pragma unroll
    for (int off = 16; off; off >>= 1) ls += __shfl_xor(ls, off);
    for (int base = 0; base < n; base += 32) {
      int e = base + l;
      int sv = 0; float wt = 0.f;
      if (e < n) {
        sv = adj_src[beg + e];
        float v = el[sv] + er_d;
        v = v > 0.f ? v : 0.2f * v;
        wt = expf(v - lm) / ls;
      }
      int cnt = min(32, n - base);
      for (int j = 0; j < cnt; ++j) {
        int s0 = __shfl(sv, gb + j);
        float w0 = __shfl(wt, gb + j);
        ushort4 f0 = *(const ushort4*)&F[(size_t)s0 * 128 + c0];
        acc.x += w0 * h2f(f0.x);
        acc.y += w0 * h2f(f0.y);
        acc.z += w0 * h2f(f0.z);
        acc.w += w0 * h2f(f0.w);
      }
    }
  }
  ushort4 o;
  o.x = f2h(fmaxf(acc.x + bv.x, 0.f));
  o.y = f2h(fmaxf(acc.y + bv.y, 0.f));
  o.z = f2h(fmaxf(acc.z + bv.z, 0.f));
  o.w = f2h(fmaxf(acc.w + bv.w, 0.f));
  *(ushort4*)&outX[(size_t)d * 128 + c0] = o;
}

// ---------------- fused outer GAT aggregation (fp32 f3 gather) ----------------
__global__ __launch_bounds__(256) void gat_aggregate_outer_kernel(
    const float* __restrict__ F, const float* __restrict__ el,
    const float* __restrict__ er, const int* __restrict__ row_ptr,
    const int* __restrict__ adj_src,
    const float* __restrict__ bias, float* __restrict__ outG) {
  const int t = threadIdx.x;
  const int l = t & 31;
  const int gb = t & 32;
  const int d = blockIdx.x * 8 + (t >> 5);
  const int c0 = l * 4;
  int beg = row_ptr[d];
  int n = row_ptr[d + 1] - beg;
  float4 bv = *(const float4*)&bias[c0];
  if (n == 0) {
    float4 o;
    o.x = fmaxf(bv.x, 0.f); o.y = fmaxf(bv.y, 0.f);
    o.z = fmaxf(bv.z, 0.f); o.w = fmaxf(bv.w, 0.f);
    *(float4*)&outG[(size_t)d * 128 + c0] = o;
    return;
  }
  float er_d = er[d];
  float4 acc = make_float4(0.f, 0.f, 0.f, 0.f);
  if (n <= 32) {
    int sv = 0; float sc = -INFINITY;
    if (l < n) {
      sv = adj_src[beg + l];
      float v = el[sv] + er_d;
      sc = v > 0.f ? v : 0.2f * v;
    }
    float m = sc;
#pragma unroll
    for (int off = 16; off; off >>= 1) m = fmaxf(m, __shfl_xor(m, off));
    float ex = (l < n) ? expf(sc - m) : 0.f;
    float s = ex;
#pragma unroll
    for (int off = 16; off; off >>= 1) s += __shfl_xor(s, off);
    float wt = ex / s;
    for (int j = 0; j < n; ++j) {
      int   s0 = __shfl(sv, gb + j);
      float w0 = __shfl(wt, gb + j);
      float4 f0 = *(const float4*)&F[(size_t)s0 * 128 + c0];
      acc.x += w0 * f0.x; acc.y += w0 * f0.y;
      acc.z += w0 * f0.z; acc.w += w0 * f0.w;
    }
  } else {
    float lm = -INFINITY;
    for (int e = l; e < n; e += 32) {
      int sv = adj_src[beg + e];
      float v = el[sv] + er_d;
      v = v > 0.f ? v : 0.2f * v;
      lm = fmaxf(lm, v);
    }
#pragma unroll
    for (int off = 16; off; off >>= 1) lm = fmaxf(lm, __shfl_xor(lm, off));
    float ls = 0.f;
    for (int e = l; e < n; e += 32) {
      int sv = adj_src[beg + e];
      float v = el[sv] + er_d;
      v = v > 0.f ? v : 0.2f * v;
      ls += expf(v - lm);
    }
#pragma unroll
    for (int off = 16; off; off >>= 1) ls += __shfl_xor(ls, off);
    for (int base = 0; base < n; base += 32) {
      int e = base + l;
      int sv = 0; float wt = 0.f;
      if (e < n) {
        sv = adj_src[beg + e];
        float v = el[sv] + er_d;
        v = v > 0.f ? v : 0.2f * v;
        wt = expf(v - lm) / ls;
      }
      int cnt = min(32, n - base);
      for (int j = 0; j < cnt; ++j) {
        int s0 = __shfl(sv, gb + j);
        float w0 = __shfl(wt, gb + j);
        float4 f0 = *(const float4*)&F[(size_t)s0 * 128 + c0];
        acc.x += w0 * f0.x; acc.y += w0 * f0.y;
        acc.z += w0 * f0.z; acc.w += w0 * f0.w;
      }
    }
  }
  float4 o;
  o.x = fmaxf(acc.x + bv.x, 0.f);
  o.y = fmaxf(acc.y + bv.y, 0.f);
  o.z = fmaxf(acc.z + bv.z, 0.f);
  o.w = fmaxf(acc.w + bv.w, 0.f);
  *(float4*)&outG[(size_t)d * 128 + c0] = o;
}

// ---------------- atomic-path edge kernels (fallback only) ----------------
static __device__ __forceinline__ void atomicMaxF(float* addr, float v) {
  int iv = __float_as_int(v);
  if (iv >= 0) atomicMax((int*)addr, iv);
  else atomicMin((unsigned int*)addr, (unsigned int)iv);
}

static __device__ __forceinline__ float edge_score(const float* el, const float* er,
                                                   int sv, int dv) {
  float v = el[sv] + er[dv];
  return v > 0.f ? v : 0.2f * v;
}

__global__ void edge_max_kernel(const float* __restrict__ el,
                                const float* __restrict__ er,
                                const int* __restrict__ src,
                                const int* __restrict__ dst,
                                float* __restrict__ m, int nE) {
  int e = blockIdx.x * 256 + threadIdx.x;
  if (e >= nE) return;
  atomicMaxF(&m[dst[e]], edge_score(el, er, src[e], dst[e]));
}

__global__ void edge_expsum_kernel(const float* __restrict__ el,
                                   const float* __restrict__ er,
                                   const float* __restrict__ m,
                                   const int* __restrict__ src,
                                   const int* __restrict__ dst,
                                   float* __restrict__ s, int nE) {
  int e = blockIdx.x * 256 + threadIdx.x;
  if (e >= nE) return;
  int d = dst[e];
  atomicAdd(&s[d], expf(edge_score(el, er, src[e], d) - m[d]));
}

__global__ __launch_bounds__(128) void edge_aggregate_kernel(
    const float* __restrict__ f, const float* __restrict__ el,
    const float* __restrict__ er, const float* __restrict__ m,
    const float* __restrict__ s, const int* __restrict__ src,
    const int* __restrict__ dst, float* __restrict__ out, int nE) {
  int e = blockIdx.x;
  int d = threadIdx.x;
  int sv = src[e], dv = dst[e];
  float alpha = expf(edge_score(el, er, sv, dv) - m[dv]) / s[dv];
  atomicAdd(&out[(size_t)dv * 128 + d], alpha * f[(size_t)sv * 128 + d]);
}

__global__ void bias_relu_kernel(float* __restrict__ x,
                                 const float* __restrict__ b, int total) {
  int i = blockIdx.x * 256 + threadIdx.x;
  if (i >= total) return;
  x[i] = fmaxf(x[i] + b[i & 127], 0.f);
}

// ---------------- sort pooling ----------------
__global__ __launch_bounds__(64) void row_max_kernel(const float* __restrict__ x,
                                                     float* __restrict__ key) {
  int node = blockIdx.x, lane = threadIdx.x;
  float v = fmaxf(x[(size_t)node * 128 + lane], x[(size_t)node * 128 + 64 + lane]);
#pragma unroll
  for (int off = 32; off; off >>= 1) v = fmaxf(v, __shfl_down(v, off));
  if (lane == 0) key[node] = v;
}

__global__ __launch_bounds__(64) void select_topk_kernel(
    const float* __restrict__ key, int* __restrict__ sel) {
  __shared__ float keys[NPG];
  int g = blockIdx.x, t = threadIdx.x;
  keys[t] = key[(size_t)g * NPG + t];
  __syncthreads();
  float myk = keys[t];
  int rank = 0;
  for (int j = 0; j < NPG; ++j) {
    float kj = keys[j];
    rank += (kj > myk) || (kj == myk && j < t);
  }
  if (rank < KK) sel[g * KK + rank] = t;
}

// fused top-k select + 8-row bitonic sort, one 1024-thread block per graph (CSR path)
__global__ __launch_bounds__(1024) void topk_sort_kernel(
    const float* __restrict__ keyb, const bfu* __restrict__ xin,
    float* __restrict__ xp) {
  __shared__ float keys[NPG];
  __shared__ int sel_l[KK];
  __shared__ float v[1024];
  int g = blockIdx.x, t = threadIdx.x;
  if (t < NPG) keys[t] = keyb[(size_t)g * NPG + t];
  __syncthreads();
  if (t < NPG) {
    float myk = keys[t];
    int rank = 0;
    for (int j = 0; j < NPG; ++j) {
      float kj = keys[j];
      rank += (kj > myk) || (kj == myk && j < t);
    }
    if (rank < KK) sel_l[rank] = t;
  }
  __syncthreads();
  int r = t >> 7, c = t & 127;
  int node = sel_l[r];
  v[t] = h2f(xin[(size_t)(g * NPG + node) * 128 + c]);
  __syncthreads();
  for (int k = 2; k <= 128; k <<= 1) {
    for (int j = k >> 1; j > 0; j >>= 1) {
      int ixj = c ^ j;
      if (ixj > c) {
        float a = v[r * 128 + c], bb = v[r * 128 + ixj];
        bool asc = ((c & k) == 0);
        if (asc ? (a > bb) : (a < bb)) { v[r * 128 + c] = bb; v[r * 128 + ixj] = a; }
      }
      __syncthreads();
    }
  }
  xp[(size_t)g * 1024 + t] = v[t];
}

template <int HF>
__global__ __launch_bounds__(128) void sort_rows_kernel(
    const void* __restrict__ xin, const int* __restrict__ sel,
    float* __restrict__ xp) {
  __shared__ float v[128];
  int b = blockIdx.x;
  int t = threadIdx.x;
  int g = b >> 3, r = b & 7;
  int node = sel[b];
  if (HF) v[t] = h2f(((const bfu*)xin)[(size_t)(g * NPG + node) * 128 + t]);
  else    v[t] = ((const float*)xin)[(size_t)(g * NPG + node) * 128 + t];
  __syncthreads();
  for (int k = 2; k <= 128; k <<= 1) {
    for (int j = k >> 1; j > 0; j >>= 1) {
      int ixj = t ^ j;
      if (ixj > t) {
        float a = v[t], bb = v[ixj];
        bool asc = ((t & k) == 0);
        if (asc ? (a > bb) : (a < bb)) { v[t] = bb; v[ixj] = a; }
      }
      __syncthreads();
    }
  }
  xp[(size_t)g * (KK * 128) + r * 128 + t] = v[t];
}

// ---------------- fused tail MLP ----------------
__global__ __launch_bounds__(128) void mlp_tail_kernel(
    const float* __restrict__ g3, const float* __restrict__ Wl,
    const float* __restrict__ bl, const float* __restrict__ Wl1,
    const float* __restrict__ bl1, const float* __restrict__ Wc,
    const float* __restrict__ bc, float* __restrict__ out) {
  __shared__ float buf[128];
  __shared__ float r0[128], r1[128];
  int g = blockIdx.x, t = threadIdx.x;
  buf[t] = g3[(size_t)g * 128 + t];
  __syncthreads();
  float a = 0.f;
  for (int k = 0; k < 128; k++) a += buf[k] * Wl[k * 128 + t];
  float t1 = fmaxf(a + bl[t], 0.f);
  __syncthreads();
  buf[t] = t1;
  __syncthreads();
  a = 0.f;
  for (int k = 0; k < 128; k++) a += buf[k] * Wl1[k * 128 + t];
  float t2 = fmaxf(a + bl1[t], 0.f);
  r0[t] = t2 * Wc[t * 2 + 0];
  r1[t] = t2 * Wc[t * 2 + 1];
  __syncthreads();
  for (int off = 64; off; off >>= 1) {
    if (t < off) { r0[t] += r0[t + off]; r1[t] += r1[t + off]; }
    __syncthreads();
  }
  if (t == 0) {
    out[g * 2 + 0] = r0[0] + bc[0];
    out[g * 2 + 1] = r1[0] + bc[1];
  }
}

// ---------------- launcher ----------------
extern "C" void kernel_launch(void* const* d_in, const int* in_sizes, int n_in,
                              void* d_out, int out_size, void* d_ws, size_t ws_size,
                              hipStream_t stream) {
  const size_t BASE_FLOATS = (size_t)NN * DD * 2 + (size_t)NN * 4;  // X,F,el,er,mx,sm
  const size_t CSR_INTS = (size_t)(NN + 1) + NN + EE + 128;          // row_ptr,cursor,adj,part
  if (ws_size < BASE_FLOATS * sizeof(float)) {
    hipMemsetAsync(d_out, 0, (size_t)out_size * sizeof(float), stream);
    return;
  }
  const bool use_csr = ws_size >= BASE_FLOATS * sizeof(float) + CSR_INTS * sizeof(int);

  const int* h      = (const int*)d_in[0];
  const int* g_src  = (const int*)d_in[1];
  const int* g_dst  = (const int*)d_in[2];
  const int* fg_src = (const int*)d_in[3];
  const int* fg_dst = (const int*)d_in[4];
  const float* temb = (const float*)d_in[5];
  const float* W1 = (const float*)d_in[6];
  const float* al1 = (const float*)d_in[7];
  const float* ar1 = (const float*)d_in[8];
  const float* b1 = (const float*)d_in[9];
  const float* W2 = (const float*)d_in[10];
  const float* al2 = (const float*)d_in[11];
  const float* ar2 = (const float*)d_in[12];
  const float* b2 = (const float*)d_in[13];
  const float* W3 = (const float*)d_in[14];
  const float* al3 = (const float*)d_in[15];
  const float* ar3 = (const float*)d_in[16];
  const float* b3 = (const float*)d_in[17];
  const float* Wf = (const float*)d_in[18];
  const float* bfv = (const float*)d_in[19];
  const float* Wl = (const float*)d_in[20];
  const float* bl = (const float*)d_in[21];
  const float* Wl1 = (const float*)d_in[22];
  const float* bl1 = (const float*)d_in[23];
  const float* Wc = (const float*)d_in[24];
  const float* bc = (const float*)d_in[25];
  float* out = (float*)d_out;

  // ---- workspace layout ----
  float* ws = (float*)d_ws;
  float* X  = ws;                    // CSR: X fp16
  float* F  = X + (size_t)NN * DD;   // CSR: adjh (build phase) -> F fp16 -> xp/f3/... 
  float* el = F + (size_t)NN * DD;
  float* er = el + NN;
  float* mx = er + NN;
  float* sm = mx + NN;
  int* row_ptr = (int*)(sm + NN);
  int* cursor  = row_ptr + NN + 1;
  int* adj_src = cursor + NN;
  int* part    = adj_src + EE;
  // rank buffer aliases X (X first written after CSR build):
  int* rankb = (int*)X;
  // adjh (uint8, EE bytes) aliases F start: dead once mfma_gemm<1> writes F
  unsigned char* adjh = (unsigned char*)F;
  // packed W tables + vocab tables live in mx/sm scratch:
  bfu* w2h = (bfu*)mx;                      // 16384
  bfu* wfh = w2h + 16384;                   // 16384
  bfu* fvh = wfh + 16384;                   // VOCAB*128
  float* elv = (float*)(fvh + VOCAB * 128 + 128);
  float* erv = elv + VOCAB;
  // outer-graph CSR aliases X start (X dead after topk_sort):
  int* ocnt  = (int*)X;               // 2048
  int* orp   = ocnt + 2048;           // 2049
  int* orank = orp + 2080;            // EFN
  int* oadj  = orank + EFN;           // EFN
  // carved from F once F is dead:
  float* xp   = F;
  float* f3   = F + 2097152;
  float* g3   = f3 + (size_t)GG * DD;
  float* t1   = g3 + (size_t)GG * DD;
  float* t2   = t1 + (size_t)GG * DD;
  float* keyb = t2 + (size_t)GG * DD;
  int*   sel  = (int*)(keyb + NN);

  const int totalND = NN * DD;

  if (use_csr) {
    bfu* Fb  = (bfu*)F;
    bfu* Xb  = (bfu*)X;
    // ---- inner CSR (dual adjacency: plain src + uint8 vocab ids) ----
    zero_int_kernel<<<NN / 256, 256, 0, stream>>>(cursor, NN);
    hist_rank_kernel<<<EE / 256, 256, 0, stream>>>(g_dst, cursor, rankb, EE);
    scan_block_kernel<<<NN / 1024, 256, 0, stream>>>(cursor, row_ptr, part);
    scan_part_kernel<<<1, 128, 0, stream>>>(part);
    scan_add_kernel<<<(NN + 255) / 256, 256, 0, stream>>>(row_ptr, part, NN, EE);
    scatter2_dual_kernel<<<EE / 256, 256, 0, stream>>>(
        g_dst, g_src, h, row_ptr, rankb, adj_src, adjh, EE);

    pack_w2_kernel<<<128, 256, 0, stream>>>(W2, Wf, w2h, wfh);
    vocab_l1_kernel<<<VOCAB, 128, 0, stream>>>(temb, W1, al1, ar1, fvh, elv, erv);

    // layer 1: aggregate from L1-resident vocab table (uint8 adjh) -> X fp16
    gat_aggregate_vocab_kernel<<<NN / 8, 256, 0, stream>>>(
        fvh, elv, erv, h, row_ptr, adjh, b1, Xb);

    // layer 2: fp16 A MFMA -> F fp16 + logits (adjh now dead); aggregate -> X fp16
    mfma_gemm<1><<<NN / 128, 256, 0, stream>>>(
        Xb, w2h, nullptr, Fb, al2, ar2, el, er, nullptr);
    gat_aggregate_csr_kernel<<<NN / 8, 256, 0, stream>>>(Fb, el, er, row_ptr, adj_src, b2, Xb);

    // linear_forward in-place (fp16) + fused fp32 row-max key
    mfma_gemm<2><<<NN / 128, 256, 0, stream>>>(
        Xb, wfh, bfv, Xb, nullptr, nullptr, nullptr, nullptr, keyb);

    // fused sort pooling -> xp (fp32)
    topk_sort_kernel<<<GG, 1024, 0, stream>>>(keyb, Xb, xp);

    // outer CSR build (multi-block; X start dead now)
    zero_int_kernel<<<GG / 256, 256, 0, stream>>>(ocnt, GG);
    hist_rank_kernel<<<EFN / 256, 256, 0, stream>>>(fg_dst, ocnt, orank, EFN);
    scan2048_kernel<<<1, 256, 0, stream>>>(ocnt, orp, EFN);
    scatter2_kernel<<<EFN / 256, 256, 0, stream>>>(fg_dst, fg_src, orp, orank, oadj, EFN);

    // outer GAT: GEMM (+fused logits) + fused aggregate
    gemm1024_kernel<<<GG / 8, 256, 0, stream>>>(xp, W3, f3, al3, ar3, el, er);
    gat_aggregate_outer_kernel<<<GG / 8, 256, 0, stream>>>(f3, el, er, orp, oadj, b3, g3);

    // fused tail
    mlp_tail_kernel<<<GG, 128, 0, stream>>>(g3, Wl, bl, Wl1, bl1, Wc, bc, out);
  } else {
    embed_relu_kernel<<<totalND / 256, 256, 0, stream>>>(temb, h, X, totalND);
    auto gat_inner = [&](const float* W, const float* al, const float* ar, const float* bb) {
      gemm_kernel<DD, 8><<<NN / 8, 128, 0, stream>>>(X, W, nullptr, F, 0);
      attn_logits_kernel<<<NN, 64, 0, stream>>>(F, al, ar, el, er);
      init_softmax_kernel<<<(NN + 255) / 256, 256, 0, stream>>>(mx, sm, NN);
      fill_f32_kernel<<<totalND / 256, 256, 0, stream>>>(X, 0.f, totalND);
      edge_max_kernel<<<(EE + 255) / 256, 256, 0, stream>>>(el, er, g_src, g_dst, mx, EE);
      edge_expsum_kernel<<<(EE + 255) / 256, 256, 0, stream>>>(el, er, mx, g_src, g_dst, sm, EE);
      edge_aggregate_kernel<<<EE, 128, 0, stream>>>(F, el, er, mx, sm, g_src, g_dst, X, EE);
      bias_relu_kernel<<<totalND / 256, 256, 0, stream>>>(X, bb, totalND);
    };
    gat_inner(W1, al1, ar1, b1);
    gat_inner(W2, al2, ar2, b2);
    gemm_kernel<DD, 8><<<NN / 8, 128, 0, stream>>>(X, Wf, bfv, X, 1);
    row_max_kernel<<<NN, 64, 0, stream>>>(X, keyb);

    select_topk_kernel<<<GG, 64, 0, stream>>>(keyb, sel);
    sort_rows_kernel<0><<<GG * KK, 128, 0, stream>>>(X, sel, xp);

    gemm1024_kernel<<<GG / 8, 256, 0, stream>>>(xp, W3, f3, al3, ar3, el, er);
    init_softmax_kernel<<<(GG + 255) / 256, 256, 0, stream>>>(mx, sm, GG);
    fill_f32_kernel<<<(GG * DD + 255) / 256, 256, 0, stream>>>(g3, 0.f, GG * DD);
    edge_max_kernel<<<(EFN + 255) / 256, 256, 0, stream>>>(el, er, fg_src, fg_dst, mx, EFN);
    edge_expsum_kernel<<<(EFN + 255) / 256, 256, 0, stream>>>(el, er, mx, fg_src, fg_dst, sm, EFN);
    edge_aggregate_kernel<<<EFN, 128, 0, stream>>>(f3, el, er, mx, sm, fg_src, fg_dst, g3, EFN);
    bias_relu_kernel<<<(GG * DD + 255) / 256, 256, 0, stream>>>(g3, b3, GG * DD);
    mlp_tail_kernel<<<GG, 128, 0, stream>>>(g3, Wl, bl, Wl1, bl1, Wc, bc, out);
  }
}